// Round 4
// baseline (403.987 us; speedup 1.0000x reference)
//
#include <hip/hip_runtime.h>
#include <cmath>

typedef _Float16 f16;
typedef _Float16 f16x8 __attribute__((ext_vector_type(8)));
typedef float f32x4 __attribute__((ext_vector_type(4)));

#define B_ 128
#define N_ 512
#define H_ 64
#define K_ 16

__device__ __forceinline__ float elu_(float x) { return x > 0.f ? x : (__expf(x) - 1.f); }
__device__ __forceinline__ unsigned umin_(unsigned a, unsigned b) { return a < b ? a : b; }
__device__ __forceinline__ unsigned umax_(unsigned a, unsigned b) { return a > b ? a : b; }
__device__ __forceinline__ f32x4 mfma16(f16x8 a, f16x8 b, f32x4 c) {
    return __builtin_amdgcn_mfma_f32_16x16x32_f16(a, b, c, 0, 0, 0);
}
__device__ __forceinline__ f32x4 splat4(float v) { f32x4 r; r[0]=v; r[1]=v; r[2]=v; r[3]=v; return r; }
__device__ __forceinline__ unsigned mbcnt_(unsigned long long mask) {
    return __builtin_amdgcn_mbcnt_hi((unsigned)(mask >> 32),
           __builtin_amdgcn_mbcnt_lo((unsigned)mask, 0u));
}

// ---------------------------------------------------------------------------
// Fused input MLP (3 layers) + EdgeConv-0 P/Q projections + sq-norms.
// grid 1024 x block 256.
// ---------------------------------------------------------------------------
__global__ __launch_bounds__(256) void mlp_kernel(const float* __restrict__ x,
        const float* __restrict__ W0, const float* __restrict__ b0,
        const float* __restrict__ W1, const float* __restrict__ b1,
        const float* __restrict__ W2, const float* __restrict__ b2,
        const float* __restrict__ We, const float* __restrict__ be,
        f16* __restrict__ hout, float* __restrict__ sqout,
        f16* __restrict__ Pout, f16* __restrict__ Qout)
{
    __shared__ f16 tile[4][16*72];
    const int lane = threadIdx.x & 63, wid = threadIdx.x >> 6;
    const int m = lane & 15, q = lane >> 4;
    const int rowbase = blockIdx.x*64 + wid*16;
    f16* tw = tile[wid];

    // ---- layer 0: A = x (K=5 padded to 32) ----
    f16x8 af0, af1;
    {
        const float* xp = x + (size_t)(rowbase + m)*5;
        #pragma unroll
        for (int jj = 0; jj < 8; ++jj) { int k = q*8+jj; af0[jj] = (k < 5) ? (f16)xp[k] : (f16)0.f; }
    }
    f32x4 acc[4];
    #pragma unroll
    for (int t = 0; t < 4; ++t) {
        f16x8 bf;
        #pragma unroll
        for (int jj = 0; jj < 8; ++jj) { int k = q*8+jj; bf[jj] = (k < 5) ? (f16)W0[k*64 + t*16+m] : (f16)0.f; }
        acc[t] = splat4(b0[t*16+m]);
        acc[t] = mfma16(af0, bf, acc[t]);
    }
    #pragma unroll
    for (int t = 0; t < 4; ++t)
        #pragma unroll
        for (int r = 0; r < 4; ++r)
            tw[(q*4+r)*72 + t*16+m] = (f16)elu_(acc[t][r]);
    __syncthreads();
    af0 = *(const f16x8*)(tw + m*72 + q*8);
    af1 = *(const f16x8*)(tw + m*72 + q*8 + 32);
    __syncthreads();

    // ---- layer 1 ----
    #pragma unroll
    for (int t = 0; t < 4; ++t) {
        f16x8 bfa, bfb;
        #pragma unroll
        for (int jj = 0; jj < 8; ++jj) {
            bfa[jj] = (f16)W1[(q*8+jj)*64 + t*16+m];
            bfb[jj] = (f16)W1[(q*8+jj+32)*64 + t*16+m];
        }
        acc[t] = splat4(b1[t*16+m]);
        acc[t] = mfma16(af0, bfa, acc[t]);
        acc[t] = mfma16(af1, bfb, acc[t]);
    }
    #pragma unroll
    for (int t = 0; t < 4; ++t)
        #pragma unroll
        for (int r = 0; r < 4; ++r)
            tw[(q*4+r)*72 + t*16+m] = (f16)elu_(acc[t][r]);
    __syncthreads();
    af0 = *(const f16x8*)(tw + m*72 + q*8);
    af1 = *(const f16x8*)(tw + m*72 + q*8 + 32);
    __syncthreads();

    // ---- layer 2 (+ h store, sq, transpose for P/Q) ----
    #pragma unroll
    for (int t = 0; t < 4; ++t) {
        f16x8 bfa, bfb;
        #pragma unroll
        for (int jj = 0; jj < 8; ++jj) {
            bfa[jj] = (f16)W2[(q*8+jj)*64 + t*16+m];
            bfb[jj] = (f16)W2[(q*8+jj+32)*64 + t*16+m];
        }
        acc[t] = splat4(b2[t*16+m]);
        acc[t] = mfma16(af0, bfa, acc[t]);
        acc[t] = mfma16(af1, bfb, acc[t]);
    }
    float vv[4][4];
    float s[4] = {0.f,0.f,0.f,0.f};
    #pragma unroll
    for (int t = 0; t < 4; ++t)
        #pragma unroll
        for (int r = 0; r < 4; ++r) {
            float v = elu_(acc[t][r]);
            vv[t][r] = v;
            hout[(size_t)(rowbase + q*4 + r)*64 + t*16 + m] = (f16)v;
            s[r] += v*v;
        }
    #pragma unroll
    for (int off = 1; off <= 8; off <<= 1) {
        #pragma unroll
        for (int r = 0; r < 4; ++r) s[r] += __shfl_xor(s[r], off);
    }
    if (m == 0) {
        #pragma unroll
        for (int r = 0; r < 4; ++r) sqout[rowbase + q*4 + r] = s[r];
    }
    #pragma unroll
    for (int t = 0; t < 4; ++t)
        #pragma unroll
        for (int r = 0; r < 4; ++r)
            tw[(q*4+r)*72 + t*16+m] = (f16)vv[t][r];
    __syncthreads();
    af0 = *(const f16x8*)(tw + m*72 + q*8);
    af1 = *(const f16x8*)(tw + m*72 + q*8 + 32);

    // ---- P = h@(We[:64]-We[64:]) + be ; Q = h@We[64:] ----
    f32x4 aP[4], aQ[4];
    #pragma unroll
    for (int t = 0; t < 4; ++t) { aP[t] = splat4(be[t*16+m]); aQ[t] = splat4(0.f); }
    #pragma unroll
    for (int cc = 0; cc < 2; ++cc) {
        const f16x8 afc = cc ? af1 : af0;
        #pragma unroll
        for (int t = 0; t < 4; ++t) {
            f16x8 bp, bq;
            #pragma unroll
            for (int jj = 0; jj < 8; ++jj) {
                float wa = We[(q*8+jj+32*cc)*64 + t*16+m];
                float wb = We[(q*8+jj+32*cc+64)*64 + t*16+m];
                bq[jj] = (f16)wb; bp[jj] = (f16)(wa - wb);
            }
            aP[t] = mfma16(afc, bp, aP[t]);
            aQ[t] = mfma16(afc, bq, aQ[t]);
        }
    }
    #pragma unroll
    for (int t = 0; t < 4; ++t)
        #pragma unroll
        for (int r = 0; r < 4; ++r) {
            Pout[(size_t)(rowbase + q*4 + r)*64 + t*16 + m] = (f16)aP[t][r];
            Qout[(size_t)(rowbase + q*4 + r)*64 + t*16 + m] = (f16)aQ[t][r];
        }
}

// ---------------------------------------------------------------------------
// kNN v4: gram strip via MFMA, then ballot-based exact top-16 (no wave sorts,
// near-zero LDS-pipe use in selection):
//  A: per-lane min8 -> 23-step bit-descend (ballot+popc) -> threshold T
//     (512-granular; guarantees >=16 keys <= T).
//  B: ballot-compact candidates <= T into scratch (cap 64; typ ~17).
//  C: 32-step exact rank-16 over compacted values -> M2 = 16th-smallest key;
//     the exactly-16 lanes with cval <= M2 store directly (set semantics).
//  Fallback to full bitonic if >64 candidates (rare; exact).
// DOPQ: fuse next EdgeConv's P/Q projection, reusing the A-fragments.
// grid 4096 x block 256.
// ---------------------------------------------------------------------------
template<bool DOPQ>
__global__ __launch_bounds__(256, 4) void knn_kernel(const f16* __restrict__ hin,
        const float* __restrict__ sq, int* __restrict__ idxout,
        const float* __restrict__ We, const float* __restrict__ be,
        f16* __restrict__ Pout, f16* __restrict__ Qout)
{
    __shared__ unsigned keys[16*514];      // pad 512->514
    __shared__ unsigned scratch[4][4][64]; // [wave][row][slot]
    const int lane = threadIdx.x & 63;
    const int wid  = threadIdx.x >> 6;     // 0..3
    const int m = lane & 15, q = lane >> 4;
    const int b  = blockIdx.x >> 5;
    const int rt = blockIdx.x & 31;
    const int rowbase = rt*16;
    const f16* hb = hin + (size_t)b*N_*H_;
    const float* sqb = sq + b*N_;

    f16x8 af0, af1;
    {
        const f16* Ap = hb + (size_t)(rowbase + m)*64 + q*8;
        af0 = *(const f16x8*)Ap;
        af1 = *(const f16x8*)(Ap + 32);
    }
    for (int ct = wid; ct < 32; ct += 4) {
        const int colbase = ct*16;
        const f16* Bp = hb + (size_t)(colbase + m)*64 + q*8;
        f16x8 bf0 = *(const f16x8*)Bp;
        f16x8 bf1 = *(const f16x8*)(Bp + 32);
        f32x4 acc = splat4(0.f);
        acc = mfma16(af0, bf0, acc);
        acc = mfma16(af1, bf1, acc);
        const float sc = sqb[colbase + m];
        #pragma unroll
        for (int r = 0; r < 4; ++r) {
            float d = fmaf(-2.f, acc[r], sc);
            unsigned u = __float_as_uint(d);
            u = ((int)u < 0) ? ~u : (u | 0x80000000u);
            unsigned key = (u & 0xFFFFFE00u) | (unsigned)(colbase + m);
            const int rowin = q*4 + r;
            if (colbase + m == rowbase + rowin) key = 0xFFFFFFFFu;  // self
            keys[rowin*514 + colbase + m] = key;
        }
    }
    __syncthreads();

    // load 4 rows x 8 keys
    unsigned kk[4][8];
    #pragma unroll
    for (int rr = 0; rr < 4; ++rr) {
        const int ri = wid*4 + rr;
        #pragma unroll
        for (int s2 = 0; s2 < 8; ++s2) kk[rr][s2] = keys[ri*514 + lane + 64*s2];
    }

    // ---- Phase A: per-lane min8, 23-step ballot bit-descend threshold ----
    unsigned v[4];
    #pragma unroll
    for (int rr = 0; rr < 4; ++rr) {
        unsigned mn = kk[rr][0];
        #pragma unroll
        for (int s2 = 1; s2 < 8; ++s2) mn = umin_(mn, kk[rr][s2]);
        v[rr] = mn;
    }
    unsigned T[4] = {0u,0u,0u,0u};
    #pragma unroll
    for (int bit = 31; bit >= 9; --bit) {
        #pragma unroll
        for (int rr = 0; rr < 4; ++rr) {
            unsigned cand = T[rr] | (1u << bit);
            int c = __popcll(__ballot(v[rr] < cand));
            T[rr] = (c < 16) ? cand : T[rr];
        }
    }
    #pragma unroll
    for (int rr = 0; rr < 4; ++rr) T[rr] |= 511u;   // fill col bits

    // ---- Phase B: ballot-compact candidates <= T into scratch (cap 64) ----
    unsigned cnt[4];
    #pragma unroll
    for (int rr = 0; rr < 4; ++rr) {
        unsigned c = 0;
        #pragma unroll
        for (int s2 = 0; s2 < 8; ++s2) {
            const bool p = kk[rr][s2] <= T[rr];
            unsigned long long bal = __ballot(p);
            unsigned pos = c + mbcnt_(bal);
            if (p && pos < 64u) scratch[wid][rr][pos] = kk[rr][s2];
            c += (unsigned)__popcll(bal);
        }
        cnt[rr] = c;
    }
    __syncthreads();   // uniform; orders scratch writes before cross-lane reads

    unsigned cval[4];
    #pragma unroll
    for (int rr = 0; rr < 4; ++rr)
        cval[rr] = (lane < (int)umin_(cnt[rr], 64u)) ? scratch[wid][rr][lane] : 0xFFFFFFFFu;

    // ---- Phase C: exact rank-16 over candidates (32-step bit-descend) ----
    unsigned M2[4] = {0u,0u,0u,0u};
    #pragma unroll
    for (int bit = 31; bit >= 0; --bit) {
        #pragma unroll
        for (int rr = 0; rr < 4; ++rr) {
            unsigned cand = M2[rr] | (1u << bit);
            int c = __popcll(__ballot(cval[rr] < cand));
            M2[rr] = (c < 16) ? cand : M2[rr];
        }
    }

    #define CE_(x,y) { unsigned lo_ = umin_(a[x],a[y]); a[y] = umax_(a[x],a[y]); a[x] = lo_; }
    #define M16_ \
        CE_(0,8) CE_(1,9) CE_(2,10) CE_(3,11) CE_(4,12) CE_(5,13) CE_(6,14) CE_(7,15) \
        CE_(0,4) CE_(1,5) CE_(2,6) CE_(3,7) CE_(8,12) CE_(9,13) CE_(10,14) CE_(11,15) \
        CE_(0,2) CE_(1,3) CE_(4,6) CE_(5,7) CE_(8,10) CE_(9,11) CE_(12,14) CE_(13,15) \
        CE_(0,1) CE_(2,3) CE_(4,5) CE_(6,7) CE_(8,9) CE_(10,11) CE_(12,13) CE_(14,15)

    #pragma unroll
    for (int rr = 0; rr < 4; ++rr) {
        const int ri = wid*4 + rr;
        int* outp = idxout + ((size_t)b*N_ + rowbase + ri)*K_;
        if (cnt[rr] <= 64u) {            // wave-uniform fast path
            const bool p = cval[rr] <= M2[rr];          // exactly 16 lanes
            unsigned rank = mbcnt_(__ballot(p));
            if (p) outp[rank] = (int)(cval[rr] & 511u);
        } else {                          // rare exact fallback: full bitonic
            unsigned a[16];
            #pragma unroll
            for (int s2 = 0; s2 < 8; ++s2) a[s2] = kk[rr][s2];
            CE_(0,1) CE_(2,3) CE_(4,5) CE_(6,7)
            CE_(0,2) CE_(1,3) CE_(4,6) CE_(5,7)
            CE_(1,2) CE_(5,6)
            CE_(0,4) CE_(1,5) CE_(2,6) CE_(3,7)
            CE_(2,4) CE_(3,5)
            CE_(1,2) CE_(3,4) CE_(5,6)
            #pragma unroll
            for (int j = 0; j < 8; ++j) a[8+j] = __shfl_xor(a[7-j], 1);
            M16_
            #pragma unroll
            for (int d = 2; d <= 32; d <<= 1) {
                unsigned u2[16];
                #pragma unroll
                for (int j = 0; j < 16; ++j) u2[j] = __shfl_xor(a[j], d);
                #pragma unroll
                for (int j = 0; j < 16; ++j) a[j] = umin_(a[j], u2[15-j]);
                if (d < 32) { M16_ }
            }
            if (lane == 0) {
                #pragma unroll
                for (int j = 0; j < 16; ++j) outp[j] = (int)(a[j] & 511u);
            }
        }
    }
    #undef CE_
    #undef M16_

    // ---- fused P/Q projection for the next EdgeConv (reuses af0/af1) ----
    if (DOPQ) {
        f32x4 aP[4], aQ[4];
        #pragma unroll
        for (int t = 0; t < 4; ++t) { aP[t] = splat4(be[t*16+m]); aQ[t] = splat4(0.f); }
        #pragma unroll
        for (int cc = 0; cc < 2; ++cc) {
            const f16x8 afc = cc ? af1 : af0;
            #pragma unroll
            for (int t = 0; t < 4; ++t) {
                f16x8 bp, bq;
                #pragma unroll
                for (int jj = 0; jj < 8; ++jj) {
                    float wa = We[(q*8+jj+32*cc)*64 + t*16+m];
                    float wb = We[(q*8+jj+32*cc+64)*64 + t*16+m];
                    bq[jj] = (f16)wb; bp[jj] = (f16)(wa - wb);
                }
                aP[t] = mfma16(afc, bp, aP[t]);
                aQ[t] = mfma16(afc, bq, aQ[t]);
            }
        }
        #pragma unroll
        for (int t = 0; t < 4; ++t)
            #pragma unroll
            for (int r = 0; r < 4; ++r) {
                Pout[((size_t)b*N_ + rowbase + q*4 + r)*64 + t*16 + m] = (f16)aP[t][r];
                Qout[((size_t)b*N_ + rowbase + q*4 + r)*64 + t*16 + m] = (f16)aQ[t][r];
            }
    }
}

// ---------------------------------------------------------------------------
// EdgeConv layer2 + sum aggregation + fused sq-norm. 2-stage software
// pipeline on the P/Q gathers. grid 1024 x block 256.
// ---------------------------------------------------------------------------
__global__ __launch_bounds__(256) void edge_kernel(const f16* __restrict__ P,
        const f16* __restrict__ Q, const int* __restrict__ idx,
        const float* __restrict__ W1, const float* __restrict__ b1,
        f16* __restrict__ out, float* __restrict__ sqout)
{
    const int lane = threadIdx.x & 63;
    const int wid  = threadIdx.x >> 6;
    const int m = lane & 15, q = lane >> 4;

    f16x8 bf[2][4];
    #pragma unroll
    for (int cc = 0; cc < 2; ++cc)
        #pragma unroll
        for (int t = 0; t < 4; ++t)
            #pragma unroll
            for (int jj = 0; jj < 8; ++jj)
                bf[cc][t][jj] = (f16)W1[(q*8 + jj + 32*cc)*64 + t*16 + m];
    float bcol[4];
    #pragma unroll
    for (int t = 0; t < 4; ++t) bcol[t] = b1[t*16 + m];

    const int node0 = blockIdx.x*64 + wid*16;
    const int base  = node0 & ~(N_-1);
    const int c0a = q*8, c0b = q*8 + 32;
    int jv[16];
    #pragma unroll
    for (int i = 0; i < 16; ++i) jv[i] = idx[(size_t)(node0 + i)*K_ + m];

    f16x8 cp0, cp1, cq0, cq1, np0, np1, nq0, nq1;
    {
        const size_t qr = (size_t)(base + jv[0]);
        cp0 = *(const f16x8*)(P + (size_t)node0*64 + c0a);
        cp1 = *(const f16x8*)(P + (size_t)node0*64 + c0b);
        cq0 = *(const f16x8*)(Q + qr*64 + c0a);
        cq1 = *(const f16x8*)(Q + qr*64 + c0b);
    }
    #pragma unroll
    for (int i = 0; i < 16; ++i) {
        if (i < 15) {
            const size_t r1 = (size_t)(node0 + i + 1);
            const size_t qr = (size_t)(base + jv[i+1]);
            np0 = *(const f16x8*)(P + r1*64 + c0a);
            np1 = *(const f16x8*)(P + r1*64 + c0b);
            nq0 = *(const f16x8*)(Q + qr*64 + c0a);
            nq1 = *(const f16x8*)(Q + qr*64 + c0b);
        }
        const int r0 = node0 + i;
        f16x8 af[2];
        #pragma unroll
        for (int jj = 0; jj < 8; ++jj) {
            af[0][jj] = (f16)elu_((float)cp0[jj] + (float)cq0[jj]);
            af[1][jj] = (f16)elu_((float)cp1[jj] + (float)cq1[jj]);
        }
        f32x4 acc[4];
        #pragma unroll
        for (int t = 0; t < 4; ++t) acc[t] = splat4(bcol[t]);
        #pragma unroll
        for (int cc = 0; cc < 2; ++cc)
            #pragma unroll
            for (int t = 0; t < 4; ++t) acc[t] = mfma16(af[cc], bf[cc][t], acc[t]);
        float ssum = 0.f;
        #pragma unroll
        for (int t = 0; t < 4; ++t) {
            float s = elu_(acc[t][0]) + elu_(acc[t][1]) + elu_(acc[t][2]) + elu_(acc[t][3]);
            s += __shfl_xor(s, 16);
            s += __shfl_xor(s, 32);
            if (lane < 16) out[(size_t)r0*64 + t*16 + lane] = (f16)s;
            ssum += s*s;
        }
        #pragma unroll
        for (int off = 1; off <= 8; off <<= 1) ssum += __shfl_xor(ssum, off);
        if (lane == 0) sqout[r0] = ssum;
        cp0 = np0; cp1 = np1; cq0 = nq0; cq1 = nq1;
    }
}

// ---------------------------------------------------------------------------
// Global max-pool + 3-layer output MLP + log_softmax. grid 128.
// ---------------------------------------------------------------------------
__global__ __launch_bounds__(256) void final_kernel(const f16* __restrict__ hin,
        const float* __restrict__ Wo0, const float* __restrict__ bo0,
        const float* __restrict__ Wo1, const float* __restrict__ bo1,
        const float* __restrict__ Wo2, const float* __restrict__ bo2,
        float* __restrict__ out)
{
    __shared__ float red[4][64];
    __shared__ float g0[64], g1[64], g2[64], lg[10];
    const int t = threadIdx.x;
    const int b = blockIdx.x;
    const int f = t & 63, grp = t >> 6;
    float mx = -3.0e38f;
    for (int n = grp; n < N_; n += 4)
        mx = fmaxf(mx, (float)hin[((size_t)b*N_ + n)*64 + f]);
    red[grp][f] = mx;
    __syncthreads();
    if (t < 64) g0[t] = fmaxf(fmaxf(red[0][t], red[1][t]), fmaxf(red[2][t], red[3][t]));
    __syncthreads();
    if (t < 64) { float a = bo0[t]; for (int c = 0; c < 64; ++c) a += g0[c]*Wo0[c*64 + t]; g1[t] = elu_(a); }
    __syncthreads();
    if (t < 64) { float a = bo1[t]; for (int c = 0; c < 64; ++c) a += g1[c]*Wo1[c*64 + t]; g2[t] = elu_(a); }
    __syncthreads();
    if (t < 10) { float a = bo2[t]; for (int c = 0; c < 64; ++c) a += g2[c]*Wo2[c*10 + t]; lg[t] = a; }
    __syncthreads();
    if (t == 0) {
        float mxl = lg[0];
        for (int i = 1; i < 10; ++i) mxl = fmaxf(mxl, lg[i]);
        float s = 0.f;
        for (int i = 0; i < 10; ++i) s += expf(lg[i] - mxl);
        const float lse = mxl + logf(s);
        for (int i = 0; i < 10; ++i) out[b*10 + i] = lg[i] - lse;
    }
}

extern "C" void kernel_launch(void* const* d_in, const int* in_sizes, int n_in,
                              void* d_out, int out_size, void* d_ws, size_t ws_size,
                              hipStream_t stream) {
    const float* x     = (const float*)d_in[0];
    const float* W_in0 = (const float*)d_in[1];
    const float* b_in0 = (const float*)d_in[2];
    const float* W_in1 = (const float*)d_in[3];
    const float* b_in1 = (const float*)d_in[4];
    const float* W_in2 = (const float*)d_in[5];
    const float* b_in2 = (const float*)d_in[6];
    const float* W_e0  = (const float*)d_in[7];   // [2,128,64]
    const float* b_e0  = (const float*)d_in[8];   // [2,64]
    const float* W_e1  = (const float*)d_in[9];   // [2,64,64]
    const float* b_e1  = (const float*)d_in[10];  // [2,64]
    const float* Wo0   = (const float*)d_in[11];
    const float* bo0   = (const float*)d_in[12];
    const float* Wo1   = (const float*)d_in[13];
    const float* bo1   = (const float*)d_in[14];
    const float* Wo2   = (const float*)d_in[15];
    const float* bo2   = (const float*)d_in[16];

    char* ws = (char*)d_ws;
    f16*   hA   = (f16*)(ws);                       // 8 MB
    f16*   hB   = (f16*)(ws + 8388608);             // 8 MB
    f16*   Pb   = (f16*)(ws + 16777216);            // 8 MB
    f16*   Qb   = (f16*)(ws + 25165824);            // 8 MB
    int*   idxb = (int*)(ws + 33554432);            // 4 MB
    float* sqb  = (float*)(ws + 37748736);          // 256 KB

    // fused input MLP + P0/Q0 + sq
    mlp_kernel<<<1024, 256, 0, stream>>>(x, W_in0, b_in0, W_in1, b_in1, W_in2, b_in2,
                                         W_e0, b_e0, hA, sqb, Pb, Qb);
    // block 0
    knn_kernel<false><<<4096, 256, 0, stream>>>(hA, sqb, idxb, nullptr, nullptr, nullptr, nullptr);
    edge_kernel<<<1024, 256, 0, stream>>>(Pb, Qb, idxb, W_e1, b_e1, hB, sqb);
    // block 1 (knn fuses P1/Q1 projection)
    knn_kernel<true><<<4096, 256, 0, stream>>>(hB, sqb, idxb, W_e0 + 8192, b_e0 + 64, Pb, Qb);
    edge_kernel<<<1024, 256, 0, stream>>>(Pb, Qb, idxb, W_e1 + 4096, b_e1 + 64, hA, sqb);

    final_kernel<<<128, 256, 0, stream>>>(hA, Wo0, bo0, Wo1, bo1, Wo2, bo2, (float*)d_out);
}

// Round 5
// 344.891 us; speedup vs baseline: 1.1713x; 1.1713x over previous
//
#include <hip/hip_runtime.h>
#include <cmath>

typedef _Float16 f16;
typedef _Float16 f16x8 __attribute__((ext_vector_type(8)));
typedef float f32x4 __attribute__((ext_vector_type(4)));

#define B_ 128
#define N_ 512
#define H_ 64
#define K_ 16

__device__ __forceinline__ float elu_(float x) { return x > 0.f ? x : (__expf(x) - 1.f); }
__device__ __forceinline__ unsigned umin_(unsigned a, unsigned b) { return a < b ? a : b; }
__device__ __forceinline__ unsigned umax_(unsigned a, unsigned b) { return a > b ? a : b; }
__device__ __forceinline__ f32x4 mfma16(f16x8 a, f16x8 b, f32x4 c) {
    return __builtin_amdgcn_mfma_f32_16x16x32_f16(a, b, c, 0, 0, 0);
}
__device__ __forceinline__ f32x4 splat4(float v) { f32x4 r; r[0]=v; r[1]=v; r[2]=v; r[3]=v; return r; }
__device__ __forceinline__ unsigned mbcnt_(unsigned long long mask) {
    return __builtin_amdgcn_mbcnt_hi((unsigned)(mask >> 32),
           __builtin_amdgcn_mbcnt_lo((unsigned)mask, 0u));
}

// ---------------------------------------------------------------------------
// Fused input MLP (3 layers) + EdgeConv-0 P/Q projections + sq-norms.
// grid 1024 x block 256.
// ---------------------------------------------------------------------------
__global__ __launch_bounds__(256) void mlp_kernel(const float* __restrict__ x,
        const float* __restrict__ W0, const float* __restrict__ b0,
        const float* __restrict__ W1, const float* __restrict__ b1,
        const float* __restrict__ W2, const float* __restrict__ b2,
        const float* __restrict__ We, const float* __restrict__ be,
        f16* __restrict__ hout, float* __restrict__ sqout,
        f16* __restrict__ Pout, f16* __restrict__ Qout)
{
    __shared__ f16 tile[4][16*72];
    const int lane = threadIdx.x & 63, wid = threadIdx.x >> 6;
    const int m = lane & 15, q = lane >> 4;
    const int rowbase = blockIdx.x*64 + wid*16;
    f16* tw = tile[wid];

    // ---- layer 0: A = x (K=5 padded to 32) ----
    f16x8 af0, af1;
    {
        const float* xp = x + (size_t)(rowbase + m)*5;
        #pragma unroll
        for (int jj = 0; jj < 8; ++jj) { int k = q*8+jj; af0[jj] = (k < 5) ? (f16)xp[k] : (f16)0.f; }
    }
    f32x4 acc[4];
    #pragma unroll
    for (int t = 0; t < 4; ++t) {
        f16x8 bf;
        #pragma unroll
        for (int jj = 0; jj < 8; ++jj) { int k = q*8+jj; bf[jj] = (k < 5) ? (f16)W0[k*64 + t*16+m] : (f16)0.f; }
        acc[t] = splat4(b0[t*16+m]);
        acc[t] = mfma16(af0, bf, acc[t]);
    }
    #pragma unroll
    for (int t = 0; t < 4; ++t)
        #pragma unroll
        for (int r = 0; r < 4; ++r)
            tw[(q*4+r)*72 + t*16+m] = (f16)elu_(acc[t][r]);
    __syncthreads();
    af0 = *(const f16x8*)(tw + m*72 + q*8);
    af1 = *(const f16x8*)(tw + m*72 + q*8 + 32);
    __syncthreads();

    // ---- layer 1 ----
    #pragma unroll
    for (int t = 0; t < 4; ++t) {
        f16x8 bfa, bfb;
        #pragma unroll
        for (int jj = 0; jj < 8; ++jj) {
            bfa[jj] = (f16)W1[(q*8+jj)*64 + t*16+m];
            bfb[jj] = (f16)W1[(q*8+jj+32)*64 + t*16+m];
        }
        acc[t] = splat4(b1[t*16+m]);
        acc[t] = mfma16(af0, bfa, acc[t]);
        acc[t] = mfma16(af1, bfb, acc[t]);
    }
    #pragma unroll
    for (int t = 0; t < 4; ++t)
        #pragma unroll
        for (int r = 0; r < 4; ++r)
            tw[(q*4+r)*72 + t*16+m] = (f16)elu_(acc[t][r]);
    __syncthreads();
    af0 = *(const f16x8*)(tw + m*72 + q*8);
    af1 = *(const f16x8*)(tw + m*72 + q*8 + 32);
    __syncthreads();

    // ---- layer 2 (+ h store, sq, transpose for P/Q) ----
    #pragma unroll
    for (int t = 0; t < 4; ++t) {
        f16x8 bfa, bfb;
        #pragma unroll
        for (int jj = 0; jj < 8; ++jj) {
            bfa[jj] = (f16)W2[(q*8+jj)*64 + t*16+m];
            bfb[jj] = (f16)W2[(q*8+jj+32)*64 + t*16+m];
        }
        acc[t] = splat4(b2[t*16+m]);
        acc[t] = mfma16(af0, bfa, acc[t]);
        acc[t] = mfma16(af1, bfb, acc[t]);
    }
    float vv[4][4];
    float s[4] = {0.f,0.f,0.f,0.f};
    #pragma unroll
    for (int t = 0; t < 4; ++t)
        #pragma unroll
        for (int r = 0; r < 4; ++r) {
            float v = elu_(acc[t][r]);
            vv[t][r] = v;
            hout[(size_t)(rowbase + q*4 + r)*64 + t*16 + m] = (f16)v;
            s[r] += v*v;
        }
    #pragma unroll
    for (int off = 1; off <= 8; off <<= 1) {
        #pragma unroll
        for (int r = 0; r < 4; ++r) s[r] += __shfl_xor(s[r], off);
    }
    if (m == 0) {
        #pragma unroll
        for (int r = 0; r < 4; ++r) sqout[rowbase + q*4 + r] = s[r];
    }
    #pragma unroll
    for (int t = 0; t < 4; ++t)
        #pragma unroll
        for (int r = 0; r < 4; ++r)
            tw[(q*4+r)*72 + t*16+m] = (f16)vv[t][r];
    __syncthreads();
    af0 = *(const f16x8*)(tw + m*72 + q*8);
    af1 = *(const f16x8*)(tw + m*72 + q*8 + 32);

    // ---- P = h@(We[:64]-We[64:]) + be ; Q = h@We[64:] ----
    f32x4 aP[4], aQ[4];
    #pragma unroll
    for (int t = 0; t < 4; ++t) { aP[t] = splat4(be[t*16+m]); aQ[t] = splat4(0.f); }
    #pragma unroll
    for (int cc = 0; cc < 2; ++cc) {
        const f16x8 afc = cc ? af1 : af0;
        #pragma unroll
        for (int t = 0; t < 4; ++t) {
            f16x8 bp, bq;
            #pragma unroll
            for (int jj = 0; jj < 8; ++jj) {
                float wa = We[(q*8+jj+32*cc)*64 + t*16+m];
                float wb = We[(q*8+jj+32*cc+64)*64 + t*16+m];
                bq[jj] = (f16)wb; bp[jj] = (f16)(wa - wb);
            }
            aP[t] = mfma16(afc, bp, aP[t]);
            aQ[t] = mfma16(afc, bq, aQ[t]);
        }
    }
    #pragma unroll
    for (int t = 0; t < 4; ++t)
        #pragma unroll
        for (int r = 0; r < 4; ++r) {
            Pout[(size_t)(rowbase + q*4 + r)*64 + t*16 + m] = (f16)aP[t][r];
            Qout[(size_t)(rowbase + q*4 + r)*64 + t*16 + m] = (f16)aQ[t][r];
        }
}

// ---------------------------------------------------------------------------
// kNN v5: gram strip via MFMA + ballot-based exact top-16.
// LDS: 16 rows x 512 keys, XOR-swizzled (col ^ (row<<1)) -> exactly 32 KB
// -> 5 blocks/CU (20 waves). Phase-B scratch unioned into the wave's own
// (dead after kk load) keys region -> no second barrier.
// DOPQ: fused next-layer P/Q projection, wave-split by output col-block t=wid.
// grid 4096 x block 256.
// ---------------------------------------------------------------------------
#define KIDX(row, col) ((row)*512 + ((col) ^ ((row) << 1)))

template<bool DOPQ>
__global__ __launch_bounds__(256, 5) void knn_kernel(const f16* __restrict__ hin,
        const float* __restrict__ sq, int* __restrict__ idxout,
        const float* __restrict__ We, const float* __restrict__ be,
        f16* __restrict__ Pout, f16* __restrict__ Qout)
{
    __shared__ unsigned keys[16*512];      // 32768 B exactly
    const int lane = threadIdx.x & 63;
    const int wid  = threadIdx.x >> 6;     // 0..3
    const int m = lane & 15, q = lane >> 4;
    const int b  = blockIdx.x >> 5;
    const int rt = blockIdx.x & 31;
    const int rowbase = rt*16;
    const f16* hb = hin + (size_t)b*N_*H_;
    const float* sqb = sq + b*N_;

    f16x8 af0, af1;
    {
        const f16* Ap = hb + (size_t)(rowbase + m)*64 + q*8;
        af0 = *(const f16x8*)Ap;
        af1 = *(const f16x8*)(Ap + 32);
    }
    for (int ct = wid; ct < 32; ct += 4) {
        const int colbase = ct*16;
        const f16* Bp = hb + (size_t)(colbase + m)*64 + q*8;
        f16x8 bf0 = *(const f16x8*)Bp;
        f16x8 bf1 = *(const f16x8*)(Bp + 32);
        f32x4 acc = splat4(0.f);
        acc = mfma16(af0, bf0, acc);
        acc = mfma16(af1, bf1, acc);
        const float sc = sqb[colbase + m];
        #pragma unroll
        for (int r = 0; r < 4; ++r) {
            float d = fmaf(-2.f, acc[r], sc);
            unsigned u = __float_as_uint(d);
            u = ((int)u < 0) ? ~u : (u | 0x80000000u);
            unsigned key = (u & 0xFFFFFE00u) | (unsigned)(colbase + m);
            const int rowin = q*4 + r;
            if (colbase + m == rowbase + rowin) key = 0xFFFFFFFFu;  // self
            keys[KIDX(rowin, colbase + m)] = key;
        }
    }
    __syncthreads();

    // load own 4 rows x 8 keys into registers (keys region then dead for us)
    unsigned kk[4][8];
    #pragma unroll
    for (int rr = 0; rr < 4; ++rr) {
        const int ri = wid*4 + rr;
        #pragma unroll
        for (int s2 = 0; s2 < 8; ++s2) kk[rr][s2] = keys[KIDX(ri, lane + 64*s2)];
    }
    // scratch lives inside this wave's own consumed keys rows (8 KB region)
    unsigned* scr = keys + wid*4*512;

    // ---- Phase A: per-lane min8, 23-step ballot bit-descend threshold ----
    unsigned v[4];
    #pragma unroll
    for (int rr = 0; rr < 4; ++rr) {
        unsigned mn = kk[rr][0];
        #pragma unroll
        for (int s2 = 1; s2 < 8; ++s2) mn = umin_(mn, kk[rr][s2]);
        v[rr] = mn;
    }
    unsigned T[4] = {0u,0u,0u,0u};
    #pragma unroll
    for (int bit = 31; bit >= 9; --bit) {
        #pragma unroll
        for (int rr = 0; rr < 4; ++rr) {
            unsigned cand = T[rr] | (1u << bit);
            int c = __popcll(__ballot(v[rr] < cand));
            T[rr] = (c < 16) ? cand : T[rr];
        }
    }
    #pragma unroll
    for (int rr = 0; rr < 4; ++rr) T[rr] |= 511u;   // fill col bits

    // ---- Phase B: ballot-compact candidates <= T (cap 64; typ ~17) ----
    unsigned cnt[4];
    #pragma unroll
    for (int rr = 0; rr < 4; ++rr) {
        unsigned c = 0;
        #pragma unroll
        for (int s2 = 0; s2 < 8; ++s2) {
            const bool p = kk[rr][s2] <= T[rr];
            unsigned long long bal = __ballot(p);
            unsigned pos = c + mbcnt_(bal);
            if (p && pos < 64u) scr[rr*64 + pos] = kk[rr][s2];
            c += (unsigned)__popcll(bal);
        }
        cnt[rr] = c;
    }
    // same-wave LDS RAW is ordered by lgkmcnt; no barrier needed
    unsigned cval[4];
    #pragma unroll
    for (int rr = 0; rr < 4; ++rr)
        cval[rr] = (lane < (int)umin_(cnt[rr], 64u)) ? scr[rr*64 + lane] : 0xFFFFFFFFu;

    // ---- Phase C: exact rank-16 over candidates (32-step bit-descend) ----
    unsigned M2[4] = {0u,0u,0u,0u};
    #pragma unroll
    for (int bit = 31; bit >= 0; --bit) {
        #pragma unroll
        for (int rr = 0; rr < 4; ++rr) {
            unsigned cand = M2[rr] | (1u << bit);
            int c = __popcll(__ballot(cval[rr] < cand));
            M2[rr] = (c < 16) ? cand : M2[rr];
        }
    }

    #define CE_(x,y) { unsigned lo_ = umin_(a[x],a[y]); a[y] = umax_(a[x],a[y]); a[x] = lo_; }
    #define M16_ \
        CE_(0,8) CE_(1,9) CE_(2,10) CE_(3,11) CE_(4,12) CE_(5,13) CE_(6,14) CE_(7,15) \
        CE_(0,4) CE_(1,5) CE_(2,6) CE_(3,7) CE_(8,12) CE_(9,13) CE_(10,14) CE_(11,15) \
        CE_(0,2) CE_(1,3) CE_(4,6) CE_(5,7) CE_(8,10) CE_(9,11) CE_(12,14) CE_(13,15) \
        CE_(0,1) CE_(2,3) CE_(4,5) CE_(6,7) CE_(8,9) CE_(10,11) CE_(12,13) CE_(14,15)

    #pragma unroll
    for (int rr = 0; rr < 4; ++rr) {
        const int ri = wid*4 + rr;
        int* outp = idxout + ((size_t)b*N_ + rowbase + ri)*K_;
        if (cnt[rr] <= 64u) {            // wave-uniform fast path
            const bool p = cval[rr] <= M2[rr];          // exactly 16 lanes
            unsigned rank = mbcnt_(__ballot(p));
            if (p) outp[rank] = (int)(cval[rr] & 511u);
        } else {                          // rare exact fallback: full bitonic
            unsigned a[16];
            #pragma unroll
            for (int s2 = 0; s2 < 8; ++s2) a[s2] = kk[rr][s2];
            CE_(0,1) CE_(2,3) CE_(4,5) CE_(6,7)
            CE_(0,2) CE_(1,3) CE_(4,6) CE_(5,7)
            CE_(1,2) CE_(5,6)
            CE_(0,4) CE_(1,5) CE_(2,6) CE_(3,7)
            CE_(2,4) CE_(3,5)
            CE_(1,2) CE_(3,4) CE_(5,6)
            #pragma unroll
            for (int j = 0; j < 8; ++j) a[8+j] = __shfl_xor(a[7-j], 1);
            M16_
            #pragma unroll
            for (int d = 2; d <= 32; d <<= 1) {
                unsigned u2[16];
                #pragma unroll
                for (int j = 0; j < 16; ++j) u2[j] = __shfl_xor(a[j], d);
                #pragma unroll
                for (int j = 0; j < 16; ++j) a[j] = umin_(a[j], u2[15-j]);
                if (d < 32) { M16_ }
            }
            if (lane == 0) {
                #pragma unroll
                for (int j = 0; j < 16; ++j) outp[j] = (int)(a[j] & 511u);
            }
        }
    }
    #undef CE_
    #undef M16_

    // ---- fused P/Q projection, wave-split: wave wid computes col-block t=wid
    if (DOPQ) {
        const int t = wid;
        f32x4 aP = splat4(be[t*16+m]), aQ = splat4(0.f);
        #pragma unroll
        for (int cc = 0; cc < 2; ++cc) {
            const f16x8 afc = cc ? af1 : af0;
            f16x8 bp, bq;
            #pragma unroll
            for (int jj = 0; jj < 8; ++jj) {
                float wa = We[(q*8+jj+32*cc)*64 + t*16+m];
                float wb = We[(q*8+jj+32*cc+64)*64 + t*16+m];
                bq[jj] = (f16)wb; bp[jj] = (f16)(wa - wb);
            }
            aP = mfma16(afc, bp, aP);
            aQ = mfma16(afc, bq, aQ);
        }
        #pragma unroll
        for (int r = 0; r < 4; ++r) {
            Pout[((size_t)b*N_ + rowbase + q*4 + r)*64 + t*16 + m] = (f16)aP[r];
            Qout[((size_t)b*N_ + rowbase + q*4 + r)*64 + t*16 + m] = (f16)aQ[r];
        }
    }
}

// ---------------------------------------------------------------------------
// EdgeConv layer2 + sum aggregation + fused sq-norm (R3 form — the pipelined
// variant regressed via register pressure). grid 1024 x block 256.
// ---------------------------------------------------------------------------
__global__ __launch_bounds__(256) void edge_kernel(const f16* __restrict__ P,
        const f16* __restrict__ Q, const int* __restrict__ idx,
        const float* __restrict__ W1, const float* __restrict__ b1,
        f16* __restrict__ out, float* __restrict__ sqout)
{
    const int lane = threadIdx.x & 63;
    const int wid  = threadIdx.x >> 6;
    const int m = lane & 15, q = lane >> 4;

    f16x8 bf[2][4];
    #pragma unroll
    for (int cc = 0; cc < 2; ++cc)
        #pragma unroll
        for (int t = 0; t < 4; ++t)
            #pragma unroll
            for (int jj = 0; jj < 8; ++jj)
                bf[cc][t][jj] = (f16)W1[(q*8 + jj + 32*cc)*64 + t*16 + m];
    float bcol[4];
    #pragma unroll
    for (int t = 0; t < 4; ++t) bcol[t] = b1[t*16 + m];

    const int node0 = blockIdx.x*64 + wid*16;
    for (int i = 0; i < 16; ++i) {
        const int r0 = node0 + i;
        const int j = idx[(size_t)r0*K_ + m];
        const int qrow = (r0 & ~(N_-1)) + j;
        f16x8 af[2];
        #pragma unroll
        for (int cc = 0; cc < 2; ++cc) {
            const int c0 = q*8 + 32*cc;
            f16x8 pv = *(const f16x8*)(P + (size_t)r0*64 + c0);
            f16x8 qv = *(const f16x8*)(Q + (size_t)qrow*64 + c0);
            #pragma unroll
            for (int jj = 0; jj < 8; ++jj)
                af[cc][jj] = (f16)elu_((float)pv[jj] + (float)qv[jj]);
        }
        f32x4 acc[4];
        #pragma unroll
        for (int t = 0; t < 4; ++t) acc[t] = splat4(bcol[t]);
        #pragma unroll
        for (int cc = 0; cc < 2; ++cc)
            #pragma unroll
            for (int t = 0; t < 4; ++t) acc[t] = mfma16(af[cc], bf[cc][t], acc[t]);
        float ssum = 0.f;
        #pragma unroll
        for (int t = 0; t < 4; ++t) {
            float s = elu_(acc[t][0]) + elu_(acc[t][1]) + elu_(acc[t][2]) + elu_(acc[t][3]);
            s += __shfl_xor(s, 16);
            s += __shfl_xor(s, 32);
            if (lane < 16) out[(size_t)r0*64 + t*16 + lane] = (f16)s;
            ssum += s*s;
        }
        #pragma unroll
        for (int off = 1; off <= 8; off <<= 1) ssum += __shfl_xor(ssum, off);
        if (lane == 0) sqout[r0] = ssum;
    }
}

// ---------------------------------------------------------------------------
// Global max-pool + 3-layer output MLP + log_softmax. grid 128.
// ---------------------------------------------------------------------------
__global__ __launch_bounds__(256) void final_kernel(const f16* __restrict__ hin,
        const float* __restrict__ Wo0, const float* __restrict__ bo0,
        const float* __restrict__ Wo1, const float* __restrict__ bo1,
        const float* __restrict__ Wo2, const float* __restrict__ bo2,
        float* __restrict__ out)
{
    __shared__ float red[4][64];
    __shared__ float g0[64], g1[64], g2[64], lg[10];
    const int t = threadIdx.x;
    const int b = blockIdx.x;
    const int f = t & 63, grp = t >> 6;
    float mx = -3.0e38f;
    for (int n = grp; n < N_; n += 4)
        mx = fmaxf(mx, (float)hin[((size_t)b*N_ + n)*64 + f]);
    red[grp][f] = mx;
    __syncthreads();
    if (t < 64) g0[t] = fmaxf(fmaxf(red[0][t], red[1][t]), fmaxf(red[2][t], red[3][t]));
    __syncthreads();
    if (t < 64) { float a = bo0[t]; for (int c = 0; c < 64; ++c) a += g0[c]*Wo0[c*64 + t]; g1[t] = elu_(a); }
    __syncthreads();
    if (t < 64) { float a = bo1[t]; for (int c = 0; c < 64; ++c) a += g1[c]*Wo1[c*64 + t]; g2[t] = elu_(a); }
    __syncthreads();
    if (t < 10) { float a = bo2[t]; for (int c = 0; c < 64; ++c) a += g2[c]*Wo2[c*10 + t]; lg[t] = a; }
    __syncthreads();
    if (t == 0) {
        float mxl = lg[0];
        for (int i = 1; i < 10; ++i) mxl = fmaxf(mxl, lg[i]);
        float s = 0.f;
        for (int i = 0; i < 10; ++i) s += expf(lg[i] - mxl);
        const float lse = mxl + logf(s);
        for (int i = 0; i < 10; ++i) out[b*10 + i] = lg[i] - lse;
    }
}

extern "C" void kernel_launch(void* const* d_in, const int* in_sizes, int n_in,
                              void* d_out, int out_size, void* d_ws, size_t ws_size,
                              hipStream_t stream) {
    const float* x     = (const float*)d_in[0];
    const float* W_in0 = (const float*)d_in[1];
    const float* b_in0 = (const float*)d_in[2];
    const float* W_in1 = (const float*)d_in[3];
    const float* b_in1 = (const float*)d_in[4];
    const float* W_in2 = (const float*)d_in[5];
    const float* b_in2 = (const float*)d_in[6];
    const float* W_e0  = (const float*)d_in[7];   // [2,128,64]
    const float* b_e0  = (const float*)d_in[8];   // [2,64]
    const float* W_e1  = (const float*)d_in[9];   // [2,64,64]
    const float* b_e1  = (const float*)d_in[10];  // [2,64]
    const float* Wo0   = (const float*)d_in[11];
    const float* bo0   = (const float*)d_in[12];
    const float* Wo1   = (const float*)d_in[13];
    const float* bo1   = (const float*)d_in[14];
    const float* Wo2   = (const float*)d_in[15];
    const float* bo2   = (const float*)d_in[16];

    char* ws = (char*)d_ws;
    f16*   hA   = (f16*)(ws);                       // 8 MB
    f16*   hB   = (f16*)(ws + 8388608);             // 8 MB
    f16*   Pb   = (f16*)(ws + 16777216);            // 8 MB
    f16*   Qb   = (f16*)(ws + 25165824);            // 8 MB
    int*   idxb = (int*)(ws + 33554432);            // 4 MB
    float* sqb  = (float*)(ws + 37748736);          // 256 KB

    // fused input MLP + P0/Q0 + sq
    mlp_kernel<<<1024, 256, 0, stream>>>(x, W_in0, b_in0, W_in1, b_in1, W_in2, b_in2,
                                         W_e0, b_e0, hA, sqb, Pb, Qb);
    // block 0
    knn_kernel<false><<<4096, 256, 0, stream>>>(hA, sqb, idxb, nullptr, nullptr, nullptr, nullptr);
    edge_kernel<<<1024, 256, 0, stream>>>(Pb, Qb, idxb, W_e1, b_e1, hB, sqb);
    // block 1 (knn fuses P1/Q1 projection, wave-split by t)
    knn_kernel<true><<<4096, 256, 0, stream>>>(hB, sqb, idxb, W_e0 + 8192, b_e0 + 64, Pb, Qb);
    edge_kernel<<<1024, 256, 0, stream>>>(Pb, Qb, idxb, W_e1 + 4096, b_e1 + 64, hA, sqb);

    final_kernel<<<128, 256, 0, stream>>>(hA, Wo0, bo0, Wo1, bo1, Wo2, bo2, (float*)d_out);
}

// Round 6
// 303.834 us; speedup vs baseline: 1.3296x; 1.1351x over previous
//
#include <hip/hip_runtime.h>
#include <cmath>

typedef _Float16 f16;
typedef _Float16 f16x8 __attribute__((ext_vector_type(8)));
typedef float f32x4 __attribute__((ext_vector_type(4)));

#define B_ 128
#define N_ 512
#define H_ 64
#define K_ 16

__device__ __forceinline__ float elu_(float x) { return x > 0.f ? x : (__expf(x) - 1.f); }
__device__ __forceinline__ unsigned umin_(unsigned a, unsigned b) { return a < b ? a : b; }
__device__ __forceinline__ f32x4 mfma16(f16x8 a, f16x8 b, f32x4 c) {
    return __builtin_amdgcn_mfma_f32_16x16x32_f16(a, b, c, 0, 0, 0);
}
__device__ __forceinline__ f32x4 splat4(float v) { f32x4 r; r[0]=v; r[1]=v; r[2]=v; r[3]=v; return r; }
__device__ __forceinline__ unsigned mbcnt_(unsigned long long mask) {
    return __builtin_amdgcn_mbcnt_hi((unsigned)(mask >> 32),
           __builtin_amdgcn_mbcnt_lo((unsigned)mask, 0u));
}

// ---------------------------------------------------------------------------
// Fused input MLP (3 layers) + EdgeConv-0 P/Q projections + sq-norms.
// grid 1024 x block 256.
// ---------------------------------------------------------------------------
__global__ __launch_bounds__(256) void mlp_kernel(const float* __restrict__ x,
        const float* __restrict__ W0, const float* __restrict__ b0,
        const float* __restrict__ W1, const float* __restrict__ b1,
        const float* __restrict__ W2, const float* __restrict__ b2,
        const float* __restrict__ We, const float* __restrict__ be,
        f16* __restrict__ hout, float* __restrict__ sqout,
        f16* __restrict__ Pout, f16* __restrict__ Qout)
{
    __shared__ f16 tile[4][16*72];
    const int lane = threadIdx.x & 63, wid = threadIdx.x >> 6;
    const int m = lane & 15, q = lane >> 4;
    const int rowbase = blockIdx.x*64 + wid*16;
    f16* tw = tile[wid];

    // ---- layer 0: A = x (K=5 padded to 32) ----
    f16x8 af0, af1;
    {
        const float* xp = x + (size_t)(rowbase + m)*5;
        #pragma unroll
        for (int jj = 0; jj < 8; ++jj) { int k = q*8+jj; af0[jj] = (k < 5) ? (f16)xp[k] : (f16)0.f; }
    }
    f32x4 acc[4];
    #pragma unroll
    for (int t = 0; t < 4; ++t) {
        f16x8 bf;
        #pragma unroll
        for (int jj = 0; jj < 8; ++jj) { int k = q*8+jj; bf[jj] = (k < 5) ? (f16)W0[k*64 + t*16+m] : (f16)0.f; }
        acc[t] = splat4(b0[t*16+m]);
        acc[t] = mfma16(af0, bf, acc[t]);
    }
    #pragma unroll
    for (int t = 0; t < 4; ++t)
        #pragma unroll
        for (int r = 0; r < 4; ++r)
            tw[(q*4+r)*72 + t*16+m] = (f16)elu_(acc[t][r]);
    __syncthreads();
    af0 = *(const f16x8*)(tw + m*72 + q*8);
    af1 = *(const f16x8*)(tw + m*72 + q*8 + 32);
    __syncthreads();

    // ---- layer 1 ----
    #pragma unroll
    for (int t = 0; t < 4; ++t) {
        f16x8 bfa, bfb;
        #pragma unroll
        for (int jj = 0; jj < 8; ++jj) {
            bfa[jj] = (f16)W1[(q*8+jj)*64 + t*16+m];
            bfb[jj] = (f16)W1[(q*8+jj+32)*64 + t*16+m];
        }
        acc[t] = splat4(b1[t*16+m]);
        acc[t] = mfma16(af0, bfa, acc[t]);
        acc[t] = mfma16(af1, bfb, acc[t]);
    }
    #pragma unroll
    for (int t = 0; t < 4; ++t)
        #pragma unroll
        for (int r = 0; r < 4; ++r)
            tw[(q*4+r)*72 + t*16+m] = (f16)elu_(acc[t][r]);
    __syncthreads();
    af0 = *(const f16x8*)(tw + m*72 + q*8);
    af1 = *(const f16x8*)(tw + m*72 + q*8 + 32);
    __syncthreads();

    // ---- layer 2 (+ h store, sq, transpose for P/Q) ----
    #pragma unroll
    for (int t = 0; t < 4; ++t) {
        f16x8 bfa, bfb;
        #pragma unroll
        for (int jj = 0; jj < 8; ++jj) {
            bfa[jj] = (f16)W2[(q*8+jj)*64 + t*16+m];
            bfb[jj] = (f16)W2[(q*8+jj+32)*64 + t*16+m];
        }
        acc[t] = splat4(b2[t*16+m]);
        acc[t] = mfma16(af0, bfa, acc[t]);
        acc[t] = mfma16(af1, bfb, acc[t]);
    }
    float vv[4][4];
    float s[4] = {0.f,0.f,0.f,0.f};
    #pragma unroll
    for (int t = 0; t < 4; ++t)
        #pragma unroll
        for (int r = 0; r < 4; ++r) {
            float v = elu_(acc[t][r]);
            vv[t][r] = v;
            hout[(size_t)(rowbase + q*4 + r)*64 + t*16 + m] = (f16)v;
            s[r] += v*v;
        }
    #pragma unroll
    for (int off = 1; off <= 8; off <<= 1) {
        #pragma unroll
        for (int r = 0; r < 4; ++r) s[r] += __shfl_xor(s[r], off);
    }
    if (m == 0) {
        #pragma unroll
        for (int r = 0; r < 4; ++r) sqout[rowbase + q*4 + r] = s[r];
    }
    #pragma unroll
    for (int t = 0; t < 4; ++t)
        #pragma unroll
        for (int r = 0; r < 4; ++r)
            tw[(q*4+r)*72 + t*16+m] = (f16)vv[t][r];
    __syncthreads();
    af0 = *(const f16x8*)(tw + m*72 + q*8);
    af1 = *(const f16x8*)(tw + m*72 + q*8 + 32);

    // ---- P = h@(We[:64]-We[64:]) + be ; Q = h@We[64:] ----
    f32x4 aP[4], aQ[4];
    #pragma unroll
    for (int t = 0; t < 4; ++t) { aP[t] = splat4(be[t*16+m]); aQ[t] = splat4(0.f); }
    #pragma unroll
    for (int cc = 0; cc < 2; ++cc) {
        const f16x8 afc = cc ? af1 : af0;
        #pragma unroll
        for (int t = 0; t < 4; ++t) {
            f16x8 bp, bq;
            #pragma unroll
            for (int jj = 0; jj < 8; ++jj) {
                float wa = We[(q*8+jj+32*cc)*64 + t*16+m];
                float wb = We[(q*8+jj+32*cc+64)*64 + t*16+m];
                bq[jj] = (f16)wb; bp[jj] = (f16)(wa - wb);
            }
            aP[t] = mfma16(afc, bp, aP[t]);
            aQ[t] = mfma16(afc, bq, aQ[t]);
        }
    }
    #pragma unroll
    for (int t = 0; t < 4; ++t)
        #pragma unroll
        for (int r = 0; r < 4; ++r) {
            Pout[(size_t)(rowbase + q*4 + r)*64 + t*16 + m] = (f16)aP[t][r];
            Qout[(size_t)(rowbase + q*4 + r)*64 + t*16 + m] = (f16)aQ[t][r];
        }
}

// ---------------------------------------------------------------------------
// kNN v6: block 512 (8 waves, 2 rows/wave) -> 4 blocks/CU = 32 waves/CU at
// 32 KB LDS. Gram strip via MFMA (8 waves split 32 col-tiles). Selection:
// ballot bit-descend threshold -> ballot-compact -> ballot rank-16, all on
// the VALU/SALU pipes. kk reload via physical-offset ds_read_b128 (selection
// has set semantics; keys embed their col). No bitonic fallback: >64
// candidates needs >64 keys in one 512-ulp distance granule (P~0 for
// continuous features); if it ever fired we'd select among the first 64.
// DOPQ: fused next-layer P/Q projection; waves 0-3 -> P, 4-7 -> Q.
// grid 4096 x block 512.
// ---------------------------------------------------------------------------
#define KIDX(row, col) ((row)*512 + ((col) ^ ((row) << 1)))

template<bool DOPQ>
__global__ __launch_bounds__(512, 8) void knn_kernel(const f16* __restrict__ hin,
        const float* __restrict__ sq, int* __restrict__ idxout,
        const float* __restrict__ We, const float* __restrict__ be,
        f16* __restrict__ Pout, f16* __restrict__ Qout)
{
    __shared__ unsigned keys[16*512];      // 32768 B exactly
    const int lane = threadIdx.x & 63;
    const int wid  = threadIdx.x >> 6;     // 0..7
    const int m = lane & 15, q = lane >> 4;
    const int b  = blockIdx.x >> 5;
    const int rt = blockIdx.x & 31;
    const int rowbase = rt*16;
    const f16* hb = hin + (size_t)b*N_*H_;
    const float* sqb = sq + b*N_;

    f16x8 af0, af1;
    {
        const f16* Ap = hb + (size_t)(rowbase + m)*64 + q*8;
        af0 = *(const f16x8*)Ap;
        af1 = *(const f16x8*)(Ap + 32);
    }
    #pragma unroll
    for (int ct = wid; ct < 32; ct += 8) {
        const int colbase = ct*16;
        const f16* Bp = hb + (size_t)(colbase + m)*64 + q*8;
        f16x8 bf0 = *(const f16x8*)Bp;
        f16x8 bf1 = *(const f16x8*)(Bp + 32);
        f32x4 acc = splat4(0.f);
        acc = mfma16(af0, bf0, acc);
        acc = mfma16(af1, bf1, acc);
        const float sc = sqb[colbase + m];
        #pragma unroll
        for (int r = 0; r < 4; ++r) {
            float d = fmaf(-2.f, acc[r], sc);       // sq_i dropped: row-constant
            unsigned u = __float_as_uint(d);
            u = ((int)u < 0) ? ~u : (u | 0x80000000u);   // monotone order map
            unsigned key = (u & 0xFFFFFE00u) | (unsigned)(colbase + m);
            const int rowin = q*4 + r;
            if (colbase + m == rowbase + rowin) key = 0xFFFFFFFFu;  // self
            keys[KIDX(rowin, colbase + m)] = key;
        }
    }
    __syncthreads();

    // load own 2 rows: physical-offset b128 reads (any lane<->key partition ok)
    unsigned kk[2][8];
    #pragma unroll
    for (int rr = 0; rr < 2; ++rr) {
        const int ri = wid*2 + rr;
        *(uint4*)&kk[rr][0] = *(const uint4*)(keys + ri*512 + lane*4);
        *(uint4*)&kk[rr][4] = *(const uint4*)(keys + ri*512 + 256 + lane*4);
    }
    // scratch in this wave's own (now dead) keys rows
    unsigned* scr = keys + wid*2*512;

    // ---- Phase A: per-lane min8, 23-step ballot bit-descend threshold ----
    unsigned v[2];
    #pragma unroll
    for (int rr = 0; rr < 2; ++rr) {
        unsigned mn = kk[rr][0];
        #pragma unroll
        for (int s2 = 1; s2 < 8; ++s2) mn = umin_(mn, kk[rr][s2]);
        v[rr] = mn;
    }
    unsigned T[2] = {0u,0u};
    #pragma unroll
    for (int bit = 31; bit >= 9; --bit) {
        #pragma unroll
        for (int rr = 0; rr < 2; ++rr) {
            unsigned cand = T[rr] | (1u << bit);
            int c = __popcll(__ballot(v[rr] < cand));
            T[rr] = (c < 16) ? cand : T[rr];
        }
    }
    T[0] |= 511u; T[1] |= 511u;   // fill col bits

    // ---- Phase B: ballot-compact candidates <= T (cap 64; typ ~17) ----
    unsigned cnt[2];
    #pragma unroll
    for (int rr = 0; rr < 2; ++rr) {
        unsigned c = 0;
        #pragma unroll
        for (int s2 = 0; s2 < 8; ++s2) {
            const bool p = kk[rr][s2] <= T[rr];
            unsigned long long bal = __ballot(p);
            unsigned pos = c + mbcnt_(bal);
            if (p && pos < 64u) scr[rr*64 + pos] = kk[rr][s2];
            c += (unsigned)__popcll(bal);
        }
        cnt[rr] = c;
    }
    // same-wave LDS RAW ordered by lgkmcnt; no barrier needed
    unsigned cval[2];
    #pragma unroll
    for (int rr = 0; rr < 2; ++rr)
        cval[rr] = (lane < (int)umin_(cnt[rr], 64u)) ? scr[rr*64 + lane] : 0xFFFFFFFFu;

    // ---- Phase C: exact rank-16 over candidates (32-step bit-descend) ----
    unsigned M2[2] = {0u,0u};
    #pragma unroll
    for (int bit = 31; bit >= 0; --bit) {
        #pragma unroll
        for (int rr = 0; rr < 2; ++rr) {
            unsigned cand = M2[rr] | (1u << bit);
            int c = __popcll(__ballot(cval[rr] < cand));
            M2[rr] = (c < 16) ? cand : M2[rr];
        }
    }
    #pragma unroll
    for (int rr = 0; rr < 2; ++rr) {
        const int ri = wid*2 + rr;
        int* outp = idxout + ((size_t)b*N_ + rowbase + ri)*K_;
        const bool p = cval[rr] <= M2[rr];          // exactly 16 lanes
        unsigned rank = mbcnt_(__ballot(p));
        if (p) outp[rank] = (int)(cval[rr] & 511u);
    }

    // ---- fused P/Q projection: waves 0-3 -> P col-block wid, 4-7 -> Q ----
    if (DOPQ) {
        const int t = wid & 3;
        f32x4 acc = (wid < 4) ? splat4(be[t*16+m]) : splat4(0.f);
        #pragma unroll
        for (int cc = 0; cc < 2; ++cc) {
            const f16x8 afc = cc ? af1 : af0;
            f16x8 bb;
            if (wid < 4) {
                #pragma unroll
                for (int jj = 0; jj < 8; ++jj) {
                    float wa = We[(q*8+jj+32*cc)*64 + t*16+m];
                    float wb = We[(q*8+jj+32*cc+64)*64 + t*16+m];
                    bb[jj] = (f16)(wa - wb);
                }
            } else {
                #pragma unroll
                for (int jj = 0; jj < 8; ++jj)
                    bb[jj] = (f16)We[(q*8+jj+32*cc+64)*64 + t*16+m];
            }
            acc = mfma16(afc, bb, acc);
        }
        f16* outp = (wid < 4) ? Pout : Qout;
        #pragma unroll
        for (int r = 0; r < 4; ++r)
            outp[((size_t)b*N_ + rowbase + q*4 + r)*64 + t*16 + m] = (f16)acc[r];
    }
}

// ---------------------------------------------------------------------------
// EdgeConv layer2 + sum aggregation + fused sq-norm. grid 1024 x block 256.
// ---------------------------------------------------------------------------
__global__ __launch_bounds__(256) void edge_kernel(const f16* __restrict__ P,
        const f16* __restrict__ Q, const int* __restrict__ idx,
        const float* __restrict__ W1, const float* __restrict__ b1,
        f16* __restrict__ out, float* __restrict__ sqout)
{
    const int lane = threadIdx.x & 63;
    const int wid  = threadIdx.x >> 6;
    const int m = lane & 15, q = lane >> 4;

    f16x8 bf[2][4];
    #pragma unroll
    for (int cc = 0; cc < 2; ++cc)
        #pragma unroll
        for (int t = 0; t < 4; ++t)
            #pragma unroll
            for (int jj = 0; jj < 8; ++jj)
                bf[cc][t][jj] = (f16)W1[(q*8 + jj + 32*cc)*64 + t*16 + m];
    float bcol[4];
    #pragma unroll
    for (int t = 0; t < 4; ++t) bcol[t] = b1[t*16 + m];

    const int node0 = blockIdx.x*64 + wid*16;
    for (int i = 0; i < 16; ++i) {
        const int r0 = node0 + i;
        const int j = idx[(size_t)r0*K_ + m];
        const int qrow = (r0 & ~(N_-1)) + j;
        f16x8 af[2];
        #pragma unroll
        for (int cc = 0; cc < 2; ++cc) {
            const int c0 = q*8 + 32*cc;
            f16x8 pv = *(const f16x8*)(P + (size_t)r0*64 + c0);
            f16x8 qv = *(const f16x8*)(Q + (size_t)qrow*64 + c0);
            #pragma unroll
            for (int jj = 0; jj < 8; ++jj)
                af[cc][jj] = (f16)elu_((float)pv[jj] + (float)qv[jj]);
        }
        f32x4 acc[4];
        #pragma unroll
        for (int t = 0; t < 4; ++t) acc[t] = splat4(bcol[t]);
        #pragma unroll
        for (int cc = 0; cc < 2; ++cc)
            #pragma unroll
            for (int t = 0; t < 4; ++t) acc[t] = mfma16(af[cc], bf[cc][t], acc[t]);
        float ssum = 0.f;
        #pragma unroll
        for (int t = 0; t < 4; ++t) {
            float s = elu_(acc[t][0]) + elu_(acc[t][1]) + elu_(acc[t][2]) + elu_(acc[t][3]);
            s += __shfl_xor(s, 16);
            s += __shfl_xor(s, 32);
            if (lane < 16) out[(size_t)r0*64 + t*16 + lane] = (f16)s;
            ssum += s*s;
        }
        #pragma unroll
        for (int off = 1; off <= 8; off <<= 1) ssum += __shfl_xor(ssum, off);
        if (lane == 0) sqout[r0] = ssum;
    }
}

// ---------------------------------------------------------------------------
// Global max-pool (vectorized f16x8 loads + LDS tree) + 3-layer output MLP
// (4-way split dots) + log_softmax. grid 128 x block 256.
// ---------------------------------------------------------------------------
__global__ __launch_bounds__(256) void final_kernel(const f16* __restrict__ hin,
        const float* __restrict__ Wo0, const float* __restrict__ bo0,
        const float* __restrict__ Wo1, const float* __restrict__ bo1,
        const float* __restrict__ Wo2, const float* __restrict__ bo2,
        float* __restrict__ out)
{
    __shared__ float smax[32][64];
    __shared__ float g0[64], g1[64], g2[64], part[4][64], lg[10];
    const int t = threadIdx.x;
    const int b = blockIdx.x;
    const int cg = t & 7, rg = t >> 3;     // col-group 0..7 (8 cols), row-group 0..31

    float mx[8];
    #pragma unroll
    for (int e = 0; e < 8; ++e) mx[e] = -3.0e38f;
    #pragma unroll
    for (int i = 0; i < 16; ++i) {
        const int row = rg + i*32;
        f16x8 vv = *(const f16x8*)(hin + ((size_t)b*N_ + row)*64 + cg*8);
        #pragma unroll
        for (int e = 0; e < 8; ++e) mx[e] = fmaxf(mx[e], (float)vv[e]);
    }
    #pragma unroll
    for (int e = 0; e < 8; ++e) smax[rg][cg*8 + e] = mx[e];
    __syncthreads();
    for (int s = 16; s >= 1; s >>= 1) {
        if (rg < s) {
            #pragma unroll
            for (int e = 0; e < 8; ++e)
                smax[rg][cg*8+e] = fmaxf(smax[rg][cg*8+e], smax[rg+s][cg*8+e]);
        }
        __syncthreads();
    }
    if (t < 64) g0[t] = smax[0][t];
    __syncthreads();

    const int j = t & 63, p = t >> 6;
    {
        float a = 0.f;
        #pragma unroll
        for (int c = 0; c < 16; ++c) a += g0[p*16 + c]*Wo0[(p*16 + c)*64 + j];
        part[p][j] = a;
    }
    __syncthreads();
    if (t < 64) g1[t] = elu_(part[0][t] + part[1][t] + part[2][t] + part[3][t] + bo0[t]);
    __syncthreads();
    {
        float a = 0.f;
        #pragma unroll
        for (int c = 0; c < 16; ++c) a += g1[p*16 + c]*Wo1[(p*16 + c)*64 + j];
        part[p][j] = a;
    }
    __syncthreads();
    if (t < 64) g2[t] = elu_(part[0][t] + part[1][t] + part[2][t] + part[3][t] + bo1[t]);
    __syncthreads();
    if (t < 10) { float a = bo2[t]; for (int c = 0; c < 64; ++c) a += g2[c]*Wo2[c*10 + t]; lg[t] = a; }
    __syncthreads();
    if (t == 0) {
        float mxl = lg[0];
        for (int i = 1; i < 10; ++i) mxl = fmaxf(mxl, lg[i]);
        float s = 0.f;
        for (int i = 0; i < 10; ++i) s += expf(lg[i] - mxl);
        const float lse = mxl + logf(s);
        for (int i = 0; i < 10; ++i) out[b*10 + i] = lg[i] - lse;
    }
}

extern "C" void kernel_launch(void* const* d_in, const int* in_sizes, int n_in,
                              void* d_out, int out_size, void* d_ws, size_t ws_size,
                              hipStream_t stream) {
    const float* x     = (const float*)d_in[0];
    const float* W_in0 = (const float*)d_in[1];
    const float* b_in0 = (const float*)d_in[2];
    const float* W_in1 = (const float*)d_in[3];
    const float* b_in1 = (const float*)d_in[4];
    const float* W_in2 = (const float*)d_in[5];
    const float* b_in2 = (const float*)d_in[6];
    const float* W_e0  = (const float*)d_in[7];   // [2,128,64]
    const float* b_e0  = (const float*)d_in[8];   // [2,64]
    const float* W_e1  = (const float*)d_in[9];   // [2,64,64]
    const float* b_e1  = (const float*)d_in[10];  // [2,64]
    const float* Wo0   = (const float*)d_in[11];
    const float* bo0   = (const float*)d_in[12];
    const float* Wo1   = (const float*)d_in[13];
    const float* bo1   = (const float*)d_in[14];
    const float* Wo2   = (const float*)d_in[15];
    const float* bo2   = (const float*)d_in[16];

    char* ws = (char*)d_ws;
    f16*   hA   = (f16*)(ws);                       // 8 MB
    f16*   hB   = (f16*)(ws + 8388608);             // 8 MB
    f16*   Pb   = (f16*)(ws + 16777216);            // 8 MB
    f16*   Qb   = (f16*)(ws + 25165824);            // 8 MB
    int*   idxb = (int*)(ws + 33554432);            // 4 MB
    float* sqb  = (float*)(ws + 37748736);          // 256 KB

    // fused input MLP + P0/Q0 + sq
    mlp_kernel<<<1024, 256, 0, stream>>>(x, W_in0, b_in0, W_in1, b_in1, W_in2, b_in2,
                                         W_e0, b_e0, hA, sqb, Pb, Qb);
    // block 0
    knn_kernel<false><<<4096, 512, 0, stream>>>(hA, sqb, idxb, nullptr, nullptr, nullptr, nullptr);
    edge_kernel<<<1024, 256, 0, stream>>>(Pb, Qb, idxb, W_e1, b_e1, hB, sqb);
    // block 1 (knn fuses P1/Q1 projection; waves 0-3 P, 4-7 Q)
    knn_kernel<true><<<4096, 512, 0, stream>>>(hB, sqb, idxb, W_e0 + 8192, b_e0 + 64, Pb, Qb);
    edge_kernel<<<1024, 256, 0, stream>>>(Pb, Qb, idxb, W_e1 + 4096, b_e1 + 64, hA, sqb);

    final_kernel<<<128, 256, 0, stream>>>(hA, Wo0, bo0, Wo1, bo1, Wo2, bo2, (float*)d_out);
}

// Round 7
// 301.336 us; speedup vs baseline: 1.3407x; 1.0083x over previous
//
#include <hip/hip_runtime.h>
#include <cmath>

typedef _Float16 f16;
typedef _Float16 f16x8 __attribute__((ext_vector_type(8)));
typedef float f32x4 __attribute__((ext_vector_type(4)));

#define B_ 128
#define N_ 512
#define H_ 64
#define K_ 16

__device__ __forceinline__ float elu_(float x) { return x > 0.f ? x : (__expf(x) - 1.f); }
__device__ __forceinline__ unsigned umin_(unsigned a, unsigned b) { return a < b ? a : b; }
__device__ __forceinline__ unsigned umax_(unsigned a, unsigned b) { return a > b ? a : b; }
__device__ __forceinline__ f32x4 mfma16(f16x8 a, f16x8 b, f32x4 c) {
    return __builtin_amdgcn_mfma_f32_16x16x32_f16(a, b, c, 0, 0, 0);
}
__device__ __forceinline__ f32x4 splat4(float v) { f32x4 r; r[0]=v; r[1]=v; r[2]=v; r[3]=v; return r; }
__device__ __forceinline__ unsigned mbcnt_(unsigned long long mask) {
    return __builtin_amdgcn_mbcnt_hi((unsigned)(mask >> 32),
           __builtin_amdgcn_mbcnt_lo((unsigned)mask, 0u));
}

// ---------------------------------------------------------------------------
// Fused input MLP (3 layers) + EdgeConv-0 P/Q projections + sq-norms.
// grid 1024 x block 256.
// ---------------------------------------------------------------------------
__global__ __launch_bounds__(256) void mlp_kernel(const float* __restrict__ x,
        const float* __restrict__ W0, const float* __restrict__ b0,
        const float* __restrict__ W1, const float* __restrict__ b1,
        const float* __restrict__ W2, const float* __restrict__ b2,
        const float* __restrict__ We, const float* __restrict__ be,
        f16* __restrict__ hout, float* __restrict__ sqout,
        f16* __restrict__ Pout, f16* __restrict__ Qout)
{
    __shared__ f16 tile[4][16*72];
    const int lane = threadIdx.x & 63, wid = threadIdx.x >> 6;
    const int m = lane & 15, q = lane >> 4;
    const int rowbase = blockIdx.x*64 + wid*16;
    f16* tw = tile[wid];

    // ---- layer 0: A = x (K=5 padded to 32) ----
    f16x8 af0, af1;
    {
        const float* xp = x + (size_t)(rowbase + m)*5;
        #pragma unroll
        for (int jj = 0; jj < 8; ++jj) { int k = q*8+jj; af0[jj] = (k < 5) ? (f16)xp[k] : (f16)0.f; }
    }
    f32x4 acc[4];
    #pragma unroll
    for (int t = 0; t < 4; ++t) {
        f16x8 bf;
        #pragma unroll
        for (int jj = 0; jj < 8; ++jj) { int k = q*8+jj; bf[jj] = (k < 5) ? (f16)W0[k*64 + t*16+m] : (f16)0.f; }
        acc[t] = splat4(b0[t*16+m]);
        acc[t] = mfma16(af0, bf, acc[t]);
    }
    #pragma unroll
    for (int t = 0; t < 4; ++t)
        #pragma unroll
        for (int r = 0; r < 4; ++r)
            tw[(q*4+r)*72 + t*16+m] = (f16)elu_(acc[t][r]);
    __syncthreads();
    af0 = *(const f16x8*)(tw + m*72 + q*8);
    af1 = *(const f16x8*)(tw + m*72 + q*8 + 32);
    __syncthreads();

    // ---- layer 1 ----
    #pragma unroll
    for (int t = 0; t < 4; ++t) {
        f16x8 bfa, bfb;
        #pragma unroll
        for (int jj = 0; jj < 8; ++jj) {
            bfa[jj] = (f16)W1[(q*8+jj)*64 + t*16+m];
            bfb[jj] = (f16)W1[(q*8+jj+32)*64 + t*16+m];
        }
        acc[t] = splat4(b1[t*16+m]);
        acc[t] = mfma16(af0, bfa, acc[t]);
        acc[t] = mfma16(af1, bfb, acc[t]);
    }
    #pragma unroll
    for (int t = 0; t < 4; ++t)
        #pragma unroll
        for (int r = 0; r < 4; ++r)
            tw[(q*4+r)*72 + t*16+m] = (f16)elu_(acc[t][r]);
    __syncthreads();
    af0 = *(const f16x8*)(tw + m*72 + q*8);
    af1 = *(const f16x8*)(tw + m*72 + q*8 + 32);
    __syncthreads();

    // ---- layer 2 (+ h store, sq, transpose for P/Q) ----
    #pragma unroll
    for (int t = 0; t < 4; ++t) {
        f16x8 bfa, bfb;
        #pragma unroll
        for (int jj = 0; jj < 8; ++jj) {
            bfa[jj] = (f16)W2[(q*8+jj)*64 + t*16+m];
            bfb[jj] = (f16)W2[(q*8+jj+32)*64 + t*16+m];
        }
        acc[t] = splat4(b2[t*16+m]);
        acc[t] = mfma16(af0, bfa, acc[t]);
        acc[t] = mfma16(af1, bfb, acc[t]);
    }
    float vv[4][4];
    float s[4] = {0.f,0.f,0.f,0.f};
    #pragma unroll
    for (int t = 0; t < 4; ++t)
        #pragma unroll
        for (int r = 0; r < 4; ++r) {
            float v = elu_(acc[t][r]);
            vv[t][r] = v;
            hout[(size_t)(rowbase + q*4 + r)*64 + t*16 + m] = (f16)v;
            s[r] += v*v;
        }
    #pragma unroll
    for (int off = 1; off <= 8; off <<= 1) {
        #pragma unroll
        for (int r = 0; r < 4; ++r) s[r] += __shfl_xor(s[r], off);
    }
    if (m == 0) {
        #pragma unroll
        for (int r = 0; r < 4; ++r) sqout[rowbase + q*4 + r] = s[r];
    }
    #pragma unroll
    for (int t = 0; t < 4; ++t)
        #pragma unroll
        for (int r = 0; r < 4; ++r)
            tw[(q*4+r)*72 + t*16+m] = (f16)vv[t][r];
    __syncthreads();
    af0 = *(const f16x8*)(tw + m*72 + q*8);
    af1 = *(const f16x8*)(tw + m*72 + q*8 + 32);

    // ---- P = h@(We[:64]-We[64:]) + be ; Q = h@We[64:] ----
    f32x4 aP[4], aQ[4];
    #pragma unroll
    for (int t = 0; t < 4; ++t) { aP[t] = splat4(be[t*16+m]); aQ[t] = splat4(0.f); }
    #pragma unroll
    for (int cc = 0; cc < 2; ++cc) {
        const f16x8 afc = cc ? af1 : af0;
        #pragma unroll
        for (int t = 0; t < 4; ++t) {
            f16x8 bp, bq;
            #pragma unroll
            for (int jj = 0; jj < 8; ++jj) {
                float wa = We[(q*8+jj+32*cc)*64 + t*16+m];
                float wb = We[(q*8+jj+32*cc+64)*64 + t*16+m];
                bq[jj] = (f16)wb; bp[jj] = (f16)(wa - wb);
            }
            aP[t] = mfma16(afc, bp, aP[t]);
            aQ[t] = mfma16(afc, bq, aQ[t]);
        }
    }
    #pragma unroll
    for (int t = 0; t < 4; ++t)
        #pragma unroll
        for (int r = 0; r < 4; ++r) {
            Pout[(size_t)(rowbase + q*4 + r)*64 + t*16 + m] = (f16)aP[t][r];
            Qout[(size_t)(rowbase + q*4 + r)*64 + t*16 + m] = (f16)aQ[t][r];
        }
}

// ---------------------------------------------------------------------------
// kNN v7: block 512 (8 waves, 2 rows/wave), 4 blocks/CU at 32 KB LDS.
// Gram strip via MFMA; DOPQ (next-layer P/Q) hoisted BEFORE the barrier so
// its loads/stores overlap selection. Selection: ballot bit-descend threshold
// (23 steps) -> ballot-compact (cap 64, typ ~18) -> drop the e = cnt-16
// largest via shfl max-removal (expected e~2) -> remaining 16 = exact top-16.
// grid 4096 x block 512.
// ---------------------------------------------------------------------------
#define KIDX(row, col) ((row)*512 + ((col) ^ ((row) << 1)))

template<bool DOPQ>
__global__ __launch_bounds__(512, 8) void knn_kernel(const f16* __restrict__ hin,
        const float* __restrict__ sq, int* __restrict__ idxout,
        const float* __restrict__ We, const float* __restrict__ be,
        f16* __restrict__ Pout, f16* __restrict__ Qout)
{
    __shared__ unsigned keys[16*512];      // 32768 B exactly
    const int lane = threadIdx.x & 63;
    const int wid  = threadIdx.x >> 6;     // 0..7
    const int m = lane & 15, q = lane >> 4;
    const int b  = blockIdx.x >> 5;
    const int rt = blockIdx.x & 31;
    const int rowbase = rt*16;
    const f16* hb = hin + (size_t)b*N_*H_;
    const float* sqb = sq + b*N_;

    f16x8 af0, af1;
    {
        const f16* Ap = hb + (size_t)(rowbase + m)*64 + q*8;
        af0 = *(const f16x8*)Ap;
        af1 = *(const f16x8*)(Ap + 32);
    }
    #pragma unroll
    for (int ct = wid; ct < 32; ct += 8) {
        const int colbase = ct*16;
        const f16* Bp = hb + (size_t)(colbase + m)*64 + q*8;
        f16x8 bf0 = *(const f16x8*)Bp;
        f16x8 bf1 = *(const f16x8*)(Bp + 32);
        f32x4 acc = splat4(0.f);
        acc = mfma16(af0, bf0, acc);
        acc = mfma16(af1, bf1, acc);
        const float sc = sqb[colbase + m];
        #pragma unroll
        for (int r = 0; r < 4; ++r) {
            float d = fmaf(-2.f, acc[r], sc);       // sq_i dropped: row-constant
            unsigned u = __float_as_uint(d);
            u ^= (0x80000000u | (unsigned)((int)u >> 31));   // monotone order map
            unsigned key = (u & 0xFFFFFE00u) | (unsigned)(colbase + m);
            const int rowin = q*4 + r;
            if (colbase + m == rowbase + rowin) key = 0xFFFFFFFFu;  // self
            keys[KIDX(rowin, colbase + m)] = key;
        }
    }

    // ---- fused P/Q projection (before barrier: overlaps selection) ----
    if (DOPQ) {
        const int t = wid & 3;
        f32x4 acc = (wid < 4) ? splat4(be[t*16+m]) : splat4(0.f);
        #pragma unroll
        for (int cc = 0; cc < 2; ++cc) {
            const f16x8 afc = cc ? af1 : af0;
            f16x8 bb;
            if (wid < 4) {
                #pragma unroll
                for (int jj = 0; jj < 8; ++jj) {
                    float wa = We[(q*8+jj+32*cc)*64 + t*16+m];
                    float wb = We[(q*8+jj+32*cc+64)*64 + t*16+m];
                    bb[jj] = (f16)(wa - wb);
                }
            } else {
                #pragma unroll
                for (int jj = 0; jj < 8; ++jj)
                    bb[jj] = (f16)We[(q*8+jj+32*cc+64)*64 + t*16+m];
            }
            acc = mfma16(afc, bb, acc);
        }
        f16* outp = (wid < 4) ? Pout : Qout;
        #pragma unroll
        for (int r = 0; r < 4; ++r)
            outp[((size_t)b*N_ + rowbase + q*4 + r)*64 + t*16 + m] = (f16)acc[r];
    }
    __syncthreads();

    // load own 2 rows: physical-offset b128 reads (any lane<->key partition ok)
    unsigned kk[2][8];
    #pragma unroll
    for (int rr = 0; rr < 2; ++rr) {
        const int ri = wid*2 + rr;
        *(uint4*)&kk[rr][0] = *(const uint4*)(keys + ri*512 + lane*4);
        *(uint4*)&kk[rr][4] = *(const uint4*)(keys + ri*512 + 256 + lane*4);
    }
    // scratch in this wave's own (now dead) keys rows
    unsigned* scr = keys + wid*2*512;

    // ---- Phase A: per-lane min8, 23-step ballot bit-descend threshold ----
    unsigned v[2];
    #pragma unroll
    for (int rr = 0; rr < 2; ++rr) {
        unsigned mn = kk[rr][0];
        #pragma unroll
        for (int s2 = 1; s2 < 8; ++s2) mn = umin_(mn, kk[rr][s2]);
        v[rr] = mn;
    }
    unsigned T[2] = {0u,0u};
    #pragma unroll
    for (int bit = 31; bit >= 9; --bit) {
        #pragma unroll
        for (int rr = 0; rr < 2; ++rr) {
            unsigned cand = T[rr] | (1u << bit);
            int c = __popcll(__ballot(v[rr] < cand));
            T[rr] = (c < 16) ? cand : T[rr];
        }
    }
    T[0] |= 511u; T[1] |= 511u;   // fill col bits

    // ---- Phase B: ballot-compact candidates <= T (cap 64; typ ~18) ----
    unsigned cnt[2];
    #pragma unroll
    for (int rr = 0; rr < 2; ++rr) {
        unsigned c = 0;
        #pragma unroll
        for (int s2 = 0; s2 < 8; ++s2) {
            const bool p = kk[rr][s2] <= T[rr];
            unsigned long long bal = __ballot(p);
            unsigned pos = c + mbcnt_(bal);
            if (p && pos < 64u) scr[rr*64 + pos] = kk[rr][s2];
            c += (unsigned)__popcll(bal);
        }
        cnt[rr] = c;
    }
    // same-wave LDS RAW ordered by lgkmcnt; no barrier needed

    // ---- Phase C: drop the e = cnt-16 largest candidates (expected e~2) ----
    #pragma unroll
    for (int rr = 0; rr < 2; ++rr) {
        const unsigned cc_ = umin_(cnt[rr], 64u);
        bool act = lane < (int)cc_;
        unsigned mv = act ? scr[rr*64 + lane] : 0u;   // 0 = inactive sentinel
        const int e = (int)cc_ - 16;
        for (int it = 0; it < e; ++it) {              // wave-uniform trip count
            unsigned mx = mv;
            #pragma unroll
            for (int off = 1; off <= 32; off <<= 1) mx = umax_(mx, __shfl_xor(mx, off));
            if (mv == mx) { act = false; mv = 0u; }   // keys unique -> one lane
        }
        const int ri = wid*2 + rr;
        int* outp = idxout + ((size_t)b*N_ + rowbase + ri)*K_;
        unsigned long long bal = __ballot(act);       // exactly 16 lanes
        unsigned rank = mbcnt_(bal);
        if (act) outp[rank] = (int)(mv & 511u);
    }
}

// ---------------------------------------------------------------------------
// EdgeConv layer2 + sum aggregation + fused sq-norm. 8 nodes/wave,
// grid 2048 x block 256 -> ~8 blocks/CU for gather-latency hiding.
// ---------------------------------------------------------------------------
__global__ __launch_bounds__(256, 5) void edge_kernel(const f16* __restrict__ P,
        const f16* __restrict__ Q, const int* __restrict__ idx,
        const float* __restrict__ W1, const float* __restrict__ b1,
        f16* __restrict__ out, float* __restrict__ sqout)
{
    const int lane = threadIdx.x & 63;
    const int wid  = threadIdx.x >> 6;
    const int m = lane & 15, q = lane >> 4;

    f16x8 bf[2][4];
    #pragma unroll
    for (int cc = 0; cc < 2; ++cc)
        #pragma unroll
        for (int t = 0; t < 4; ++t)
            #pragma unroll
            for (int jj = 0; jj < 8; ++jj)
                bf[cc][t][jj] = (f16)W1[(q*8 + jj + 32*cc)*64 + t*16 + m];
    float bcol[4];
    #pragma unroll
    for (int t = 0; t < 4; ++t) bcol[t] = b1[t*16 + m];

    const int node0 = blockIdx.x*32 + wid*8;
    for (int i = 0; i < 8; ++i) {
        const int r0 = node0 + i;
        const int j = idx[(size_t)r0*K_ + m];
        const int qrow = (r0 & ~(N_-1)) + j;
        f16x8 af[2];
        #pragma unroll
        for (int cc = 0; cc < 2; ++cc) {
            const int c0 = q*8 + 32*cc;
            f16x8 pv = *(const f16x8*)(P + (size_t)r0*64 + c0);
            f16x8 qv = *(const f16x8*)(Q + (size_t)qrow*64 + c0);
            #pragma unroll
            for (int jj = 0; jj < 8; ++jj)
                af[cc][jj] = (f16)elu_((float)pv[jj] + (float)qv[jj]);
        }
        f32x4 acc[4];
        #pragma unroll
        for (int t = 0; t < 4; ++t) acc[t] = splat4(bcol[t]);
        #pragma unroll
        for (int cc = 0; cc < 2; ++cc)
            #pragma unroll
            for (int t = 0; t < 4; ++t) acc[t] = mfma16(af[cc], bf[cc][t], acc[t]);
        float ssum = 0.f;
        #pragma unroll
        for (int t = 0; t < 4; ++t) {
            float s = elu_(acc[t][0]) + elu_(acc[t][1]) + elu_(acc[t][2]) + elu_(acc[t][3]);
            s += __shfl_xor(s, 16);
            s += __shfl_xor(s, 32);
            if (lane < 16) out[(size_t)r0*64 + t*16 + lane] = (f16)s;
            ssum += s*s;
        }
        #pragma unroll
        for (int off = 1; off <= 8; off <<= 1) ssum += __shfl_xor(ssum, off);
        if (lane == 0) sqout[r0] = ssum;
    }
}

// ---------------------------------------------------------------------------
// Global max-pool (vectorized f16x8 loads + LDS tree) + 3-layer output MLP
// (4-way split dots) + log_softmax. grid 128 x block 256.
// ---------------------------------------------------------------------------
__global__ __launch_bounds__(256) void final_kernel(const f16* __restrict__ hin,
        const float* __restrict__ Wo0, const float* __restrict__ bo0,
        const float* __restrict__ Wo1, const float* __restrict__ bo1,
        const float* __restrict__ Wo2, const float* __restrict__ bo2,
        float* __restrict__ out)
{
    __shared__ float smax[32][64];
    __shared__ float g0[64], g1[64], g2[64], part[4][64], lg[10];
    const int t = threadIdx.x;
    const int b = blockIdx.x;
    const int cg = t & 7, rg = t >> 3;     // col-group 0..7 (8 cols), row-group 0..31

    float mx[8];
    #pragma unroll
    for (int e = 0; e < 8; ++e) mx[e] = -3.0e38f;
    #pragma unroll
    for (int i = 0; i < 16; ++i) {
        const int row = rg + i*32;
        f16x8 vv = *(const f16x8*)(hin + ((size_t)b*N_ + row)*64 + cg*8);
        #pragma unroll
        for (int e = 0; e < 8; ++e) mx[e] = fmaxf(mx[e], (float)vv[e]);
    }
    #pragma unroll
    for (int e = 0; e < 8; ++e) smax[rg][cg*8 + e] = mx[e];
    __syncthreads();
    for (int s = 16; s >= 1; s >>= 1) {
        if (rg < s) {
            #pragma unroll
            for (int e = 0; e < 8; ++e)
                smax[rg][cg*8+e] = fmaxf(smax[rg][cg*8+e], smax[rg+s][cg*8+e]);
        }
        __syncthreads();
    }
    if (t < 64) g0[t] = smax[0][t];
    __syncthreads();

    const int j = t & 63, p = t >> 6;
    {
        float a = 0.f;
        #pragma unroll
        for (int c = 0; c < 16; ++c) a += g0[p*16 + c]*Wo0[(p*16 + c)*64 + j];
        part[p][j] = a;
    }
    __syncthreads();
    if (t < 64) g1[t] = elu_(part[0][t] + part[1][t] + part[2][t] + part[3][t] + bo0[t]);
    __syncthreads();
    {
        float a = 0.f;
        #pragma unroll
        for (int c = 0; c < 16; ++c) a += g1[p*16 + c]*Wo1[(p*16 + c)*64 + j];
        part[p][j] = a;
    }
    __syncthreads();
    if (t < 64) g2[t] = elu_(part[0][t] + part[1][t] + part[2][t] + part[3][t] + bo1[t]);
    __syncthreads();
    if (t < 10) { float a = bo2[t]; for (int c = 0; c < 64; ++c) a += g2[c]*Wo2[c*10 + t]; lg[t] = a; }
    __syncthreads();
    if (t == 0) {
        float mxl = lg[0];
        for (int i = 1; i < 10; ++i) mxl = fmaxf(mxl, lg[i]);
        float s = 0.f;
        for (int i = 0; i < 10; ++i) s += expf(lg[i] - mxl);
        const float lse = mxl + logf(s);
        for (int i = 0; i < 10; ++i) out[b*10 + i] = lg[i] - lse;
    }
}

extern "C" void kernel_launch(void* const* d_in, const int* in_sizes, int n_in,
                              void* d_out, int out_size, void* d_ws, size_t ws_size,
                              hipStream_t stream) {
    const float* x     = (const float*)d_in[0];
    const float* W_in0 = (const float*)d_in[1];
    const float* b_in0 = (const float*)d_in[2];
    const float* W_in1 = (const float*)d_in[3];
    const float* b_in1 = (const float*)d_in[4];
    const float* W_in2 = (const float*)d_in[5];
    const float* b_in2 = (const float*)d_in[6];
    const float* W_e0  = (const float*)d_in[7];   // [2,128,64]
    const float* b_e0  = (const float*)d_in[8];   // [2,64]
    const float* W_e1  = (const float*)d_in[9];   // [2,64,64]
    const float* b_e1  = (const float*)d_in[10];  // [2,64]
    const float* Wo0   = (const float*)d_in[11];
    const float* bo0   = (const float*)d_in[12];
    const float* Wo1   = (const float*)d_in[13];
    const float* bo1   = (const float*)d_in[14];
    const float* Wo2   = (const float*)d_in[15];
    const float* bo2   = (const float*)d_in[16];

    char* ws = (char*)d_ws;
    f16*   hA   = (f16*)(ws);                       // 8 MB
    f16*   hB   = (f16*)(ws + 8388608);             // 8 MB
    f16*   Pb   = (f16*)(ws + 16777216);            // 8 MB
    f16*   Qb   = (f16*)(ws + 25165824);            // 8 MB
    int*   idxb = (int*)(ws + 33554432);            // 4 MB
    float* sqb  = (float*)(ws + 37748736);          // 256 KB

    // fused input MLP + P0/Q0 + sq
    mlp_kernel<<<1024, 256, 0, stream>>>(x, W_in0, b_in0, W_in1, b_in1, W_in2, b_in2,
                                         W_e0, b_e0, hA, sqb, Pb, Qb);
    // block 0
    knn_kernel<false><<<4096, 512, 0, stream>>>(hA, sqb, idxb, nullptr, nullptr, nullptr, nullptr);
    edge_kernel<<<2048, 256, 0, stream>>>(Pb, Qb, idxb, W_e1, b_e1, hB, sqb);
    // block 1 (knn fuses P1/Q1 projection; waves 0-3 P, 4-7 Q)
    knn_kernel<true><<<4096, 512, 0, stream>>>(hB, sqb, idxb, W_e0 + 8192, b_e0 + 64, Pb, Qb);
    edge_kernel<<<2048, 256, 0, stream>>>(Pb, Qb, idxb, W_e1 + 4096, b_e1 + 64, hA, sqb);

    final_kernel<<<128, 256, 0, stream>>>(hA, Wo0, bo0, Wo1, bo1, Wo2, bo2, (float*)d_out);
}

// Round 8
// 295.567 us; speedup vs baseline: 1.3668x; 1.0195x over previous
//
#include <hip/hip_runtime.h>
#include <hip/hip_fp16.h>
#include <cmath>

typedef _Float16 f16;
typedef _Float16 f16x8 __attribute__((ext_vector_type(8)));
typedef float f32x4 __attribute__((ext_vector_type(4)));

#define B_ 128
#define N_ 512
#define H_ 64
#define K_ 16

__device__ __forceinline__ float elu_(float x) { return x > 0.f ? x : (__expf(x) - 1.f); }
__device__ __forceinline__ unsigned umin_(unsigned a, unsigned b) { return a < b ? a : b; }
__device__ __forceinline__ unsigned umax_(unsigned a, unsigned b) { return a > b ? a : b; }
__device__ __forceinline__ f32x4 mfma16(f16x8 a, f16x8 b, f32x4 c) {
    return __builtin_amdgcn_mfma_f32_16x16x32_f16(a, b, c, 0, 0, 0);
}
__device__ __forceinline__ f32x4 splat4(float v) { f32x4 r; r[0]=v; r[1]=v; r[2]=v; r[3]=v; return r; }
__device__ __forceinline__ unsigned mbcnt_(unsigned long long mask) {
    return __builtin_amdgcn_mbcnt_hi((unsigned)(mask >> 32),
           __builtin_amdgcn_mbcnt_lo((unsigned)mask, 0u));
}
__device__ __forceinline__ f16 hexp_(f16 x) {
    __half h = *(__half*)&x; h = hexp(h); return *(f16*)&h;
}
// packed-f16 elu on 8 lanes: elu(x) = max(x,0) + exp(min(x,0)) - 1
__device__ __forceinline__ f16x8 elu8h_(f16x8 x) {
    f16x8 z; f16x8 one;
    #pragma unroll
    for (int i = 0; i < 8; ++i) { z[i] = (f16)0.f; one[i] = (f16)1.f; }
    f16x8 mx = __builtin_elementwise_max(x, z);
    f16x8 mn = __builtin_elementwise_min(x, z);
    f16x8 e;
    #pragma unroll
    for (int i = 0; i < 8; ++i) e[i] = hexp_(mn[i]);
    return mx + e - one;
}

// ---------------------------------------------------------------------------
// Fused input MLP (3 layers) + EdgeConv-0 P/Q projections + sq-norms.
// grid 1024 x block 256.
// ---------------------------------------------------------------------------
__global__ __launch_bounds__(256) void mlp_kernel(const float* __restrict__ x,
        const float* __restrict__ W0, const float* __restrict__ b0,
        const float* __restrict__ W1, const float* __restrict__ b1,
        const float* __restrict__ W2, const float* __restrict__ b2,
        const float* __restrict__ We, const float* __restrict__ be,
        f16* __restrict__ hout, float* __restrict__ sqout,
        f16* __restrict__ Pout, f16* __restrict__ Qout)
{
    __shared__ f16 tile[4][16*72];
    const int lane = threadIdx.x & 63, wid = threadIdx.x >> 6;
    const int m = lane & 15, q = lane >> 4;
    const int rowbase = blockIdx.x*64 + wid*16;
    f16* tw = tile[wid];

    // ---- layer 0: A = x (K=5 padded to 32) ----
    f16x8 af0, af1;
    {
        const float* xp = x + (size_t)(rowbase + m)*5;
        #pragma unroll
        for (int jj = 0; jj < 8; ++jj) { int k = q*8+jj; af0[jj] = (k < 5) ? (f16)xp[k] : (f16)0.f; }
    }
    f32x4 acc[4];
    #pragma unroll
    for (int t = 0; t < 4; ++t) {
        f16x8 bf;
        #pragma unroll
        for (int jj = 0; jj < 8; ++jj) { int k = q*8+jj; bf[jj] = (k < 5) ? (f16)W0[k*64 + t*16+m] : (f16)0.f; }
        acc[t] = splat4(b0[t*16+m]);
        acc[t] = mfma16(af0, bf, acc[t]);
    }
    #pragma unroll
    for (int t = 0; t < 4; ++t)
        #pragma unroll
        for (int r = 0; r < 4; ++r)
            tw[(q*4+r)*72 + t*16+m] = (f16)elu_(acc[t][r]);
    __syncthreads();
    af0 = *(const f16x8*)(tw + m*72 + q*8);
    af1 = *(const f16x8*)(tw + m*72 + q*8 + 32);
    __syncthreads();

    // ---- layer 1 ----
    #pragma unroll
    for (int t = 0; t < 4; ++t) {
        f16x8 bfa, bfb;
        #pragma unroll
        for (int jj = 0; jj < 8; ++jj) {
            bfa[jj] = (f16)W1[(q*8+jj)*64 + t*16+m];
            bfb[jj] = (f16)W1[(q*8+jj+32)*64 + t*16+m];
        }
        acc[t] = splat4(b1[t*16+m]);
        acc[t] = mfma16(af0, bfa, acc[t]);
        acc[t] = mfma16(af1, bfb, acc[t]);
    }
    #pragma unroll
    for (int t = 0; t < 4; ++t)
        #pragma unroll
        for (int r = 0; r < 4; ++r)
            tw[(q*4+r)*72 + t*16+m] = (f16)elu_(acc[t][r]);
    __syncthreads();
    af0 = *(const f16x8*)(tw + m*72 + q*8);
    af1 = *(const f16x8*)(tw + m*72 + q*8 + 32);
    __syncthreads();

    // ---- layer 2 (+ h store, sq, transpose for P/Q) ----
    #pragma unroll
    for (int t = 0; t < 4; ++t) {
        f16x8 bfa, bfb;
        #pragma unroll
        for (int jj = 0; jj < 8; ++jj) {
            bfa[jj] = (f16)W2[(q*8+jj)*64 + t*16+m];
            bfb[jj] = (f16)W2[(q*8+jj+32)*64 + t*16+m];
        }
        acc[t] = splat4(b2[t*16+m]);
        acc[t] = mfma16(af0, bfa, acc[t]);
        acc[t] = mfma16(af1, bfb, acc[t]);
    }
    float vv[4][4];
    float s[4] = {0.f,0.f,0.f,0.f};
    #pragma unroll
    for (int t = 0; t < 4; ++t)
        #pragma unroll
        for (int r = 0; r < 4; ++r) {
            float v = elu_(acc[t][r]);
            vv[t][r] = v;
            hout[(size_t)(rowbase + q*4 + r)*64 + t*16 + m] = (f16)v;
            s[r] += v*v;
        }
    #pragma unroll
    for (int off = 1; off <= 8; off <<= 1) {
        #pragma unroll
        for (int r = 0; r < 4; ++r) s[r] += __shfl_xor(s[r], off);
    }
    if (m == 0) {
        #pragma unroll
        for (int r = 0; r < 4; ++r) sqout[rowbase + q*4 + r] = s[r];
    }
    #pragma unroll
    for (int t = 0; t < 4; ++t)
        #pragma unroll
        for (int r = 0; r < 4; ++r)
            tw[(q*4+r)*72 + t*16+m] = (f16)vv[t][r];
    __syncthreads();
    af0 = *(const f16x8*)(tw + m*72 + q*8);
    af1 = *(const f16x8*)(tw + m*72 + q*8 + 32);

    // ---- P = h@(We[:64]-We[64:]) + be ; Q = h@We[64:] ----
    f32x4 aP[4], aQ[4];
    #pragma unroll
    for (int t = 0; t < 4; ++t) { aP[t] = splat4(be[t*16+m]); aQ[t] = splat4(0.f); }
    #pragma unroll
    for (int cc = 0; cc < 2; ++cc) {
        const f16x8 afc = cc ? af1 : af0;
        #pragma unroll
        for (int t = 0; t < 4; ++t) {
            f16x8 bp, bq;
            #pragma unroll
            for (int jj = 0; jj < 8; ++jj) {
                float wa = We[(q*8+jj+32*cc)*64 + t*16+m];
                float wb = We[(q*8+jj+32*cc+64)*64 + t*16+m];
                bq[jj] = (f16)wb; bp[jj] = (f16)(wa - wb);
            }
            aP[t] = mfma16(afc, bp, aP[t]);
            aQ[t] = mfma16(afc, bq, aQ[t]);
        }
    }
    #pragma unroll
    for (int t = 0; t < 4; ++t)
        #pragma unroll
        for (int r = 0; r < 4; ++r) {
            Pout[(size_t)(rowbase + q*4 + r)*64 + t*16 + m] = (f16)aP[t][r];
            Qout[(size_t)(rowbase + q*4 + r)*64 + t*16 + m] = (f16)aQ[t][r];
        }
}

// ---------------------------------------------------------------------------
// kNN v8: block 512 (8 waves, 2 rows/wave), 4 blocks/CU at 32 KB LDS.
// Gram: all 4 B-frag pairs loaded upfront (pipelined), MFMA, keypack with NO
// self-mask (self is provably the row-min; handled at rank stage), ds_writes
// use precomputed bases + immediate cti offsets. Selection: rank-17 ballot
// bit-descend threshold -> ballot-compact -> deactivate self + drop
// (actives-16) maxima via shfl max-removal. DOPQ AFTER selection (hides in
// wave overlap — R6/R7 A/B evidence). grid 4096 x block 512.
// ---------------------------------------------------------------------------
template<bool DOPQ>
__global__ __launch_bounds__(512, 8) void knn_kernel(const f16* __restrict__ hin,
        const float* __restrict__ sq, int* __restrict__ idxout,
        const float* __restrict__ We, const float* __restrict__ be,
        f16* __restrict__ Pout, f16* __restrict__ Qout)
{
    __shared__ unsigned keys[16*512];      // 32768 B exactly
    const int lane = threadIdx.x & 63;
    const int wid  = threadIdx.x >> 6;     // 0..7
    const int m = lane & 15, q = lane >> 4;
    const int b  = blockIdx.x >> 5;
    const int rt = blockIdx.x & 31;
    const int rowbase = rt*16;
    const f16* hb = hin + (size_t)b*N_*H_;
    const float* sqb = sq + b*N_;

    f16x8 af0, af1;
    {
        const f16* Ap = hb + (size_t)(rowbase + m)*64 + q*8;
        af0 = *(const f16x8*)Ap;
        af1 = *(const f16x8*)(Ap + 32);
    }
    const int colb0 = wid*16;
    // issue all B-fragment loads upfront (16 b128 in flight)
    f16x8 bf0[4], bf1[4];
    float sc[4];
    #pragma unroll
    for (int cti = 0; cti < 4; ++cti) {
        const f16* Bp = hb + (size_t)(colb0 + cti*128 + m)*64 + q*8;
        bf0[cti] = *(const f16x8*)Bp;
        bf1[cti] = *(const f16x8*)(Bp + 32);
        sc[cti] = sqb[colb0 + cti*128 + m];
    }
    // 4 LDS dword-index bases (one per r); cti adds a compile-time offset
    int base_r[4];
    #pragma unroll
    for (int r = 0; r < 4; ++r) {
        const int row = q*4 + r;
        base_r[r] = row*512 + ((colb0 + m) ^ (row << 1));
    }
    #pragma unroll
    for (int cti = 0; cti < 4; ++cti) {
        f32x4 acc = splat4(0.f);
        acc = mfma16(af0, bf0[cti], acc);
        acc = mfma16(af1, bf1[cti], acc);
        #pragma unroll
        for (int r = 0; r < 4; ++r) {
            float d = fmaf(-2.f, acc[r], sc[cti]);   // sq_i dropped: row-constant
            unsigned u = __float_as_uint(d);
            u ^= (0x80000000u | (unsigned)((int)u >> 31));   // monotone order map
            unsigned key = (u & 0xFFFFFE00u) | (unsigned)(colb0 + cti*128 + m);
            keys[base_r[r] + cti*128] = key;         // immediate offset cti*512B
        }
    }
    __syncthreads();

    // load own 2 rows: physical-offset b128 reads (any lane<->key partition ok)
    unsigned kk[2][8];
    #pragma unroll
    for (int rr = 0; rr < 2; ++rr) {
        const int ri = wid*2 + rr;
        *(uint4*)&kk[rr][0] = *(const uint4*)(keys + ri*512 + lane*4);
        *(uint4*)&kk[rr][4] = *(const uint4*)(keys + ri*512 + 256 + lane*4);
    }
    // scratch in this wave's own (now dead) keys rows
    unsigned* scr = keys + wid*2*512;

    // ---- Phase A: per-lane min8, rank-17 ballot bit-descend threshold ----
    unsigned v[2];
    #pragma unroll
    for (int rr = 0; rr < 2; ++rr) {
        unsigned mn = kk[rr][0];
        #pragma unroll
        for (int s2 = 1; s2 < 8; ++s2) mn = umin_(mn, kk[rr][s2]);
        v[rr] = mn;
    }
    unsigned T[2] = {0u,0u};
    #pragma unroll
    for (int bit = 31; bit >= 9; --bit) {
        #pragma unroll
        for (int rr = 0; rr < 2; ++rr) {
            unsigned cand = T[rr] | (1u << bit);
            int c = __popcll(__ballot(v[rr] < cand));
            T[rr] = (c < 17) ? cand : T[rr];
        }
    }
    T[0] |= 511u; T[1] |= 511u;   // fill col bits; >=17 keys <= T (incl self)

    // ---- Phase B: ballot-compact candidates <= T (cap 64; typ ~19) ----
    unsigned cnt[2];
    #pragma unroll
    for (int rr = 0; rr < 2; ++rr) {
        unsigned c = 0;
        #pragma unroll
        for (int s2 = 0; s2 < 8; ++s2) {
            const bool p = kk[rr][s2] <= T[rr];
            unsigned long long bal = __ballot(p);
            unsigned pos = c + mbcnt_(bal);
            if (p && pos < 64u) scr[rr*64 + pos] = kk[rr][s2];
            c += (unsigned)__popcll(bal);
        }
        cnt[rr] = c;
    }
    // same-wave LDS RAW ordered by lgkmcnt; no barrier needed

    // ---- Phase C: kill self, drop (actives-16) maxima (expected ~2) ----
    #pragma unroll
    for (int rr = 0; rr < 2; ++rr) {
        const unsigned cc_ = umin_(cnt[rr], 64u);
        const int ri = wid*2 + rr;
        const unsigned rowglob = (unsigned)(rowbase + ri);
        bool act = lane < (int)cc_;
        unsigned mv = act ? scr[rr*64 + lane] : 0u;   // 0 = inactive sentinel
        if (act && (mv & 511u) == rowglob) { act = false; mv = 0u; }  // self
        const int e = __popcll(__ballot(act)) - 16;
        for (int it = 0; it < e; ++it) {              // wave-uniform trip count
            unsigned mx = mv;
            #pragma unroll
            for (int off = 1; off <= 32; off <<= 1) mx = umax_(mx, __shfl_xor(mx, off));
            if (act && mv == mx) { act = false; mv = 0u; }  // keys unique
        }
        int* outp = idxout + ((size_t)b*N_ + rowglob)*K_;
        unsigned long long bal = __ballot(act);       // exactly 16 lanes
        unsigned rank = mbcnt_(bal);
        if (act) outp[rank] = (int)(mv & 511u);
    }

    // ---- fused P/Q projection AFTER selection (hides in wave overlap) ----
    if (DOPQ) {
        const int t = wid & 3;
        f32x4 acc = (wid < 4) ? splat4(be[t*16+m]) : splat4(0.f);
        #pragma unroll
        for (int cc = 0; cc < 2; ++cc) {
            const f16x8 afc = cc ? af1 : af0;
            f16x8 bb;
            if (wid < 4) {
                #pragma unroll
                for (int jj = 0; jj < 8; ++jj) {
                    float wa = We[(q*8+jj+32*cc)*64 + t*16+m];
                    float wb = We[(q*8+jj+32*cc+64)*64 + t*16+m];
                    bb[jj] = (f16)(wa - wb);
                }
            } else {
                #pragma unroll
                for (int jj = 0; jj < 8; ++jj)
                    bb[jj] = (f16)We[(q*8+jj+32*cc+64)*64 + t*16+m];
            }
            acc = mfma16(afc, bb, acc);
        }
        f16* outp = (wid < 4) ? Pout : Qout;
        #pragma unroll
        for (int r = 0; r < 4; ++r)
            outp[((size_t)b*N_ + rowbase + q*4 + r)*64 + t*16 + m] = (f16)acc[r];
    }
}

// ---------------------------------------------------------------------------
// EdgeConv layer2 + sum aggregation + fused sq-norm. Packed-f16 ELU on the
// A-fragments. 8 nodes/wave, grid 2048 x block 256.
// ---------------------------------------------------------------------------
__global__ __launch_bounds__(256, 5) void edge_kernel(const f16* __restrict__ P,
        const f16* __restrict__ Q, const int* __restrict__ idx,
        const float* __restrict__ W1, const float* __restrict__ b1,
        f16* __restrict__ out, float* __restrict__ sqout)
{
    const int lane = threadIdx.x & 63;
    const int wid  = threadIdx.x >> 6;
    const int m = lane & 15, q = lane >> 4;

    f16x8 bf[2][4];
    #pragma unroll
    for (int cc = 0; cc < 2; ++cc)
        #pragma unroll
        for (int t = 0; t < 4; ++t)
            #pragma unroll
            for (int jj = 0; jj < 8; ++jj)
                bf[cc][t][jj] = (f16)W1[(q*8 + jj + 32*cc)*64 + t*16 + m];
    float bcol[4];
    #pragma unroll
    for (int t = 0; t < 4; ++t) bcol[t] = b1[t*16 + m];

    const int node0 = blockIdx.x*32 + wid*8;
    for (int i = 0; i < 8; ++i) {
        const int r0 = node0 + i;
        const int j = idx[(size_t)r0*K_ + m];
        const int qrow = (r0 & ~(N_-1)) + j;
        f16x8 af[2];
        #pragma unroll
        for (int cc = 0; cc < 2; ++cc) {
            const int c0 = q*8 + 32*cc;
            f16x8 pv = *(const f16x8*)(P + (size_t)r0*64 + c0);
            f16x8 qv = *(const f16x8*)(Q + (size_t)qrow*64 + c0);
            af[cc] = elu8h_(pv + qv);      // packed f16 elu
        }
        f32x4 acc[4];
        #pragma unroll
        for (int t = 0; t < 4; ++t) acc[t] = splat4(bcol[t]);
        #pragma unroll
        for (int cc = 0; cc < 2; ++cc)
            #pragma unroll
            for (int t = 0; t < 4; ++t) acc[t] = mfma16(af[cc], bf[cc][t], acc[t]);
        float ssum = 0.f;
        #pragma unroll
        for (int t = 0; t < 4; ++t) {
            float s = elu_(acc[t][0]) + elu_(acc[t][1]) + elu_(acc[t][2]) + elu_(acc[t][3]);
            s += __shfl_xor(s, 16);
            s += __shfl_xor(s, 32);
            if (lane < 16) out[(size_t)r0*64 + t*16 + lane] = (f16)s;
            ssum += s*s;
        }
        #pragma unroll
        for (int off = 1; off <= 8; off <<= 1) ssum += __shfl_xor(ssum, off);
        if (lane == 0) sqout[r0] = ssum;
    }
}

// ---------------------------------------------------------------------------
// Global max-pool (vectorized f16x8 loads + LDS tree) + 3-layer output MLP
// (4-way split dots) + log_softmax. grid 128 x block 256.
// ---------------------------------------------------------------------------
__global__ __launch_bounds__(256) void final_kernel(const f16* __restrict__ hin,
        const float* __restrict__ Wo0, const float* __restrict__ bo0,
        const float* __restrict__ Wo1, const float* __restrict__ bo1,
        const float* __restrict__ Wo2, const float* __restrict__ bo2,
        float* __restrict__ out)
{
    __shared__ float smax[32][64];
    __shared__ float g0[64], g1[64], g2[64], part[4][64], lg[10];
    const int t = threadIdx.x;
    const int b = blockIdx.x;
    const int cg = t & 7, rg = t >> 3;     // col-group 0..7 (8 cols), row-group 0..31

    float mx[8];
    #pragma unroll
    for (int e = 0; e < 8; ++e) mx[e] = -3.0e38f;
    #pragma unroll
    for (int i = 0; i < 16; ++i) {
        const int row = rg + i*32;
        f16x8 vv = *(const f16x8*)(hin + ((size_t)b*N_ + row)*64 + cg*8);
        #pragma unroll
        for (int e = 0; e < 8; ++e) mx[e] = fmaxf(mx[e], (float)vv[e]);
    }
    #pragma unroll
    for (int e = 0; e < 8; ++e) smax[rg][cg*8 + e] = mx[e];
    __syncthreads();
    for (int s = 16; s >= 1; s >>= 1) {
        if (rg < s) {
            #pragma unroll
            for (int e = 0; e < 8; ++e)
                smax[rg][cg*8+e] = fmaxf(smax[rg][cg*8+e], smax[rg+s][cg*8+e]);
        }
        __syncthreads();
    }
    if (t < 64) g0[t] = smax[0][t];
    __syncthreads();

    const int j = t & 63, p = t >> 6;
    {
        float a = 0.f;
        #pragma unroll
        for (int c = 0; c < 16; ++c) a += g0[p*16 + c]*Wo0[(p*16 + c)*64 + j];
        part[p][j] = a;
    }
    __syncthreads();
    if (t < 64) g1[t] = elu_(part[0][t] + part[1][t] + part[2][t] + part[3][t] + bo0[t]);
    __syncthreads();
    {
        float a = 0.f;
        #pragma unroll
        for (int c = 0; c < 16; ++c) a += g1[p*16 + c]*Wo1[(p*16 + c)*64 + j];
        part[p][j] = a;
    }
    __syncthreads();
    if (t < 64) g2[t] = elu_(part[0][t] + part[1][t] + part[2][t] + part[3][t] + bo1[t]);
    __syncthreads();
    if (t < 10) { float a = bo2[t]; for (int c = 0; c < 64; ++c) a += g2[c]*Wo2[c*10 + t]; lg[t] = a; }
    __syncthreads();
    if (t == 0) {
        float mxl = lg[0];
        for (int i = 1; i < 10; ++i) mxl = fmaxf(mxl, lg[i]);
        float s = 0.f;
        for (int i = 0; i < 10; ++i) s += expf(lg[i] - mxl);
        const float lse = mxl + logf(s);
        for (int i = 0; i < 10; ++i) out[b*10 + i] = lg[i] - lse;
    }
}

extern "C" void kernel_launch(void* const* d_in, const int* in_sizes, int n_in,
                              void* d_out, int out_size, void* d_ws, size_t ws_size,
                              hipStream_t stream) {
    const float* x     = (const float*)d_in[0];
    const float* W_in0 = (const float*)d_in[1];
    const float* b_in0 = (const float*)d_in[2];
    const float* W_in1 = (const float*)d_in[3];
    const float* b_in1 = (const float*)d_in[4];
    const float* W_in2 = (const float*)d_in[5];
    const float* b_in2 = (const float*)d_in[6];
    const float* W_e0  = (const float*)d_in[7];   // [2,128,64]
    const float* b_e0  = (const float*)d_in[8];   // [2,64]
    const float* W_e1  = (const float*)d_in[9];   // [2,64,64]
    const float* b_e1  = (const float*)d_in[10];  // [2,64]
    const float* Wo0   = (const float*)d_in[11];
    const float* bo0   = (const float*)d_in[12];
    const float* Wo1   = (const float*)d_in[13];
    const float* bo1   = (const float*)d_in[14];
    const float* Wo2   = (const float*)d_in[15];
    const float* bo2   = (const float*)d_in[16];

    char* ws = (char*)d_ws;
    f16*   hA   = (f16*)(ws);                       // 8 MB
    f16*   hB   = (f16*)(ws + 8388608);             // 8 MB
    f16*   Pb   = (f16*)(ws + 16777216);            // 8 MB
    f16*   Qb   = (f16*)(ws + 25165824);            // 8 MB
    int*   idxb = (int*)(ws + 33554432);            // 4 MB
    float* sqb  = (float*)(ws + 37748736);          // 256 KB

    // fused input MLP + P0/Q0 + sq
    mlp_kernel<<<1024, 256, 0, stream>>>(x, W_in0, b_in0, W_in1, b_in1, W_in2, b_in2,
                                         W_e0, b_e0, hA, sqb, Pb, Qb);
    // block 0
    knn_kernel<false><<<4096, 512, 0, stream>>>(hA, sqb, idxb, nullptr, nullptr, nullptr, nullptr);
    edge_kernel<<<2048, 256, 0, stream>>>(Pb, Qb, idxb, W_e1, b_e1, hB, sqb);
    // block 1 (knn fuses P1/Q1 projection; waves 0-3 P, 4-7 Q)
    knn_kernel<true><<<4096, 512, 0, stream>>>(hB, sqb, idxb, W_e0 + 8192, b_e0 + 64, Pb, Qb);
    edge_kernel<<<2048, 256, 0, stream>>>(Pb, Qb, idxb, W_e1 + 4096, b_e1 + 64, hA, sqb);

    final_kernel<<<128, 256, 0, stream>>>(hA, Wo0, bo0, Wo1, bo1, Wo2, bo2, (float*)d_out);
}

// Round 9
// 285.346 us; speedup vs baseline: 1.4158x; 1.0358x over previous
//
#include <hip/hip_runtime.h>
#include <hip/hip_fp16.h>
#include <cmath>

typedef _Float16 f16;
typedef _Float16 f16x8 __attribute__((ext_vector_type(8)));
typedef float f32x4 __attribute__((ext_vector_type(4)));

#define B_ 128
#define N_ 512
#define H_ 64
#define K_ 16

__device__ __forceinline__ float elu_(float x) { return x > 0.f ? x : (__expf(x) - 1.f); }
__device__ __forceinline__ unsigned umin_(unsigned a, unsigned b) { return a < b ? a : b; }
__device__ __forceinline__ unsigned umax_(unsigned a, unsigned b) { return a > b ? a : b; }
__device__ __forceinline__ f32x4 mfma16(f16x8 a, f16x8 b, f32x4 c) {
    return __builtin_amdgcn_mfma_f32_16x16x32_f16(a, b, c, 0, 0, 0);
}
__device__ __forceinline__ f32x4 splat4(float v) { f32x4 r; r[0]=v; r[1]=v; r[2]=v; r[3]=v; return r; }
__device__ __forceinline__ unsigned mbcnt_(unsigned long long mask) {
    return __builtin_amdgcn_mbcnt_hi((unsigned)(mask >> 32),
           __builtin_amdgcn_mbcnt_lo((unsigned)mask, 0u));
}
__device__ __forceinline__ f16 hexp_(f16 x) {
    __half h = *(__half*)&x; h = hexp(h); return *(f16*)&h;
}
// packed-f16 elu on 8 lanes: elu(x) = max(x,0) + exp(min(x,0)) - 1
__device__ __forceinline__ f16x8 elu8h_(f16x8 x) {
    f16x8 z; f16x8 one;
    #pragma unroll
    for (int i = 0; i < 8; ++i) { z[i] = (f16)0.f; one[i] = (f16)1.f; }
    f16x8 mx = __builtin_elementwise_max(x, z);
    f16x8 mn = __builtin_elementwise_min(x, z);
    f16x8 e;
    #pragma unroll
    for (int i = 0; i < 8; ++i) e[i] = hexp_(mn[i]);
    return mx + e - one;
}
// wave-wide max via DPP (VALU pipe, no ds_swizzle); canonical shr/bcast chain.
__device__ __forceinline__ unsigned wmax64_(unsigned v) {
    v = umax_(v, (unsigned)__builtin_amdgcn_update_dpp(0, (int)v, 0x111, 0xf, 0xf, true)); // row_shr:1
    v = umax_(v, (unsigned)__builtin_amdgcn_update_dpp(0, (int)v, 0x112, 0xf, 0xf, true)); // row_shr:2
    v = umax_(v, (unsigned)__builtin_amdgcn_update_dpp(0, (int)v, 0x114, 0xf, 0xf, true)); // row_shr:4
    v = umax_(v, (unsigned)__builtin_amdgcn_update_dpp(0, (int)v, 0x118, 0xf, 0xf, true)); // row_shr:8
    v = umax_(v, (unsigned)__builtin_amdgcn_update_dpp(0, (int)v, 0x142, 0xa, 0xf, true)); // row_bcast:15
    v = umax_(v, (unsigned)__builtin_amdgcn_update_dpp(0, (int)v, 0x143, 0xc, 0xf, true)); // row_bcast:31
    return (unsigned)__builtin_amdgcn_readlane((int)v, 63);
}
// add-reduce within each 16-lane row toward lane0 (valid in lane0 of each row)
__device__ __forceinline__ float rsum16lo_(float x) {
    x += __int_as_float(__builtin_amdgcn_update_dpp(0, __float_as_int(x), 0x101, 0xf, 0xf, true));
    x += __int_as_float(__builtin_amdgcn_update_dpp(0, __float_as_int(x), 0x102, 0xf, 0xf, true));
    x += __int_as_float(__builtin_amdgcn_update_dpp(0, __float_as_int(x), 0x104, 0xf, 0xf, true));
    x += __int_as_float(__builtin_amdgcn_update_dpp(0, __float_as_int(x), 0x108, 0xf, 0xf, true));
    return x;
}

// ---------------------------------------------------------------------------
// Fused input MLP (3 layers) + sq-norms. (P0/Q0 moved into knn DOPQ.)
// grid 1024 x block 256.
// ---------------------------------------------------------------------------
__global__ __launch_bounds__(256) void mlp_kernel(const float* __restrict__ x,
        const float* __restrict__ W0, const float* __restrict__ b0,
        const float* __restrict__ W1, const float* __restrict__ b1,
        const float* __restrict__ W2, const float* __restrict__ b2,
        f16* __restrict__ hout, float* __restrict__ sqout)
{
    __shared__ f16 tile[4][16*72];
    const int lane = threadIdx.x & 63, wid = threadIdx.x >> 6;
    const int m = lane & 15, q = lane >> 4;
    const int rowbase = blockIdx.x*64 + wid*16;
    f16* tw = tile[wid];

    // ---- layer 0: A = x (K=5 padded to 32) ----
    f16x8 af0, af1;
    {
        const float* xp = x + (size_t)(rowbase + m)*5;
        #pragma unroll
        for (int jj = 0; jj < 8; ++jj) { int k = q*8+jj; af0[jj] = (k < 5) ? (f16)xp[k] : (f16)0.f; }
    }
    f32x4 acc[4];
    #pragma unroll
    for (int t = 0; t < 4; ++t) {
        f16x8 bf;
        #pragma unroll
        for (int jj = 0; jj < 8; ++jj) { int k = q*8+jj; bf[jj] = (k < 5) ? (f16)W0[k*64 + t*16+m] : (f16)0.f; }
        acc[t] = splat4(b0[t*16+m]);
        acc[t] = mfma16(af0, bf, acc[t]);
    }
    #pragma unroll
    for (int t = 0; t < 4; ++t)
        #pragma unroll
        for (int r = 0; r < 4; ++r)
            tw[(q*4+r)*72 + t*16+m] = (f16)elu_(acc[t][r]);
    __syncthreads();
    af0 = *(const f16x8*)(tw + m*72 + q*8);
    af1 = *(const f16x8*)(tw + m*72 + q*8 + 32);
    __syncthreads();

    // ---- layer 1 ----
    #pragma unroll
    for (int t = 0; t < 4; ++t) {
        f16x8 bfa, bfb;
        #pragma unroll
        for (int jj = 0; jj < 8; ++jj) {
            bfa[jj] = (f16)W1[(q*8+jj)*64 + t*16+m];
            bfb[jj] = (f16)W1[(q*8+jj+32)*64 + t*16+m];
        }
        acc[t] = splat4(b1[t*16+m]);
        acc[t] = mfma16(af0, bfa, acc[t]);
        acc[t] = mfma16(af1, bfb, acc[t]);
    }
    #pragma unroll
    for (int t = 0; t < 4; ++t)
        #pragma unroll
        for (int r = 0; r < 4; ++r)
            tw[(q*4+r)*72 + t*16+m] = (f16)elu_(acc[t][r]);
    __syncthreads();
    af0 = *(const f16x8*)(tw + m*72 + q*8);
    af1 = *(const f16x8*)(tw + m*72 + q*8 + 32);

    // ---- layer 2 (+ h store + sq) ----
    #pragma unroll
    for (int t = 0; t < 4; ++t) {
        f16x8 bfa, bfb;
        #pragma unroll
        for (int jj = 0; jj < 8; ++jj) {
            bfa[jj] = (f16)W2[(q*8+jj)*64 + t*16+m];
            bfb[jj] = (f16)W2[(q*8+jj+32)*64 + t*16+m];
        }
        acc[t] = splat4(b2[t*16+m]);
        acc[t] = mfma16(af0, bfa, acc[t]);
        acc[t] = mfma16(af1, bfb, acc[t]);
    }
    float s[4] = {0.f,0.f,0.f,0.f};
    #pragma unroll
    for (int t = 0; t < 4; ++t)
        #pragma unroll
        for (int r = 0; r < 4; ++r) {
            float v = elu_(acc[t][r]);
            hout[(size_t)(rowbase + q*4 + r)*64 + t*16 + m] = (f16)v;
            s[r] += v*v;
        }
    #pragma unroll
    for (int r = 0; r < 4; ++r) s[r] = rsum16lo_(s[r]);
    if (m == 0) {
        #pragma unroll
        for (int r = 0; r < 4; ++r) sqout[rowbase + q*4 + r] = s[r];
    }
}

// ---------------------------------------------------------------------------
// kNN v9: block 512 (8 waves, 2 rows/wave), 4 blocks/CU at 32 KB LDS.
// Gram strip via MFMA (4 B-frag pairs prefetched). Selection: rank-17 ballot
// bit-descend threshold -> batched-ballot compact (flat chains) -> kill self
// + DPP max-removal of the (actives-16) largest (VALU pipe, no ds_swizzle).
// P/Q projection for the NEXT EdgeConv fused after selection (waves 0-3 P,
// 4-7 Q) — measured-free placement. grid 4096 x block 512.
// ---------------------------------------------------------------------------
__global__ __launch_bounds__(512, 8) void knn_kernel(const f16* __restrict__ hin,
        const float* __restrict__ sq, int* __restrict__ idxout,
        const float* __restrict__ We, const float* __restrict__ be,
        f16* __restrict__ Pout, f16* __restrict__ Qout)
{
    __shared__ unsigned keys[16*512];      // 32768 B exactly
    const int lane = threadIdx.x & 63;
    const int wid  = threadIdx.x >> 6;     // 0..7
    const int m = lane & 15, q = lane >> 4;
    const int b  = blockIdx.x >> 5;
    const int rt = blockIdx.x & 31;
    const int rowbase = rt*16;
    const f16* hb = hin + (size_t)b*N_*H_;
    const float* sqb = sq + b*N_;

    f16x8 af0, af1;
    {
        const f16* Ap = hb + (size_t)(rowbase + m)*64 + q*8;
        af0 = *(const f16x8*)Ap;
        af1 = *(const f16x8*)(Ap + 32);
    }
    const int colb0 = wid*16;
    f16x8 bf0[4], bf1[4];
    float sc[4];
    #pragma unroll
    for (int cti = 0; cti < 4; ++cti) {
        const f16* Bp = hb + (size_t)(colb0 + cti*128 + m)*64 + q*8;
        bf0[cti] = *(const f16x8*)Bp;
        bf1[cti] = *(const f16x8*)(Bp + 32);
        sc[cti] = sqb[colb0 + cti*128 + m];
    }
    int base_r[4];
    #pragma unroll
    for (int r = 0; r < 4; ++r) {
        const int row = q*4 + r;
        base_r[r] = row*512 + ((colb0 + m) ^ (row << 1));
    }
    #pragma unroll
    for (int cti = 0; cti < 4; ++cti) {
        f32x4 acc = splat4(0.f);
        acc = mfma16(af0, bf0[cti], acc);
        acc = mfma16(af1, bf1[cti], acc);
        #pragma unroll
        for (int r = 0; r < 4; ++r) {
            float d = fmaf(-2.f, acc[r], sc[cti]);   // sq_i dropped: row-constant
            unsigned u = __float_as_uint(d);
            u ^= (0x80000000u | (unsigned)((int)u >> 31));   // monotone order map
            unsigned key = (u & 0xFFFFFE00u) | (unsigned)(colb0 + cti*128 + m);
            keys[base_r[r] + cti*128] = key;         // immediate offset cti*512B
        }
    }
    __syncthreads();

    // load own 2 rows: physical-offset b128 reads (any lane<->key partition ok)
    unsigned kk[2][8];
    #pragma unroll
    for (int rr = 0; rr < 2; ++rr) {
        const int ri = wid*2 + rr;
        *(uint4*)&kk[rr][0] = *(const uint4*)(keys + ri*512 + lane*4);
        *(uint4*)&kk[rr][4] = *(const uint4*)(keys + ri*512 + 256 + lane*4);
    }
    unsigned* scr = keys + wid*2*512;   // wave's own dead rows

    // ---- Phase A: per-lane min8, rank-17 ballot bit-descend threshold ----
    unsigned v[2];
    #pragma unroll
    for (int rr = 0; rr < 2; ++rr) {
        unsigned mn = kk[rr][0];
        #pragma unroll
        for (int s2 = 1; s2 < 8; ++s2) mn = umin_(mn, kk[rr][s2]);
        v[rr] = mn;
    }
    unsigned T[2] = {0u,0u};
    #pragma unroll
    for (int bit = 31; bit >= 9; --bit) {
        #pragma unroll
        for (int rr = 0; rr < 2; ++rr) {
            unsigned cand = T[rr] | (1u << bit);
            int c = __popcll(__ballot(v[rr] < cand));
            T[rr] = (c < 17) ? cand : T[rr];
        }
    }
    T[0] |= 511u; T[1] |= 511u;   // >=17 keys <= T (incl self)

    // ---- Phase B: batched-ballot compact (independent v_cmps, SALU prefix) --
    unsigned cnt[2];
    #pragma unroll
    for (int rr = 0; rr < 2; ++rr) {
        unsigned long long bal[8];
        #pragma unroll
        for (int s2 = 0; s2 < 8; ++s2) bal[s2] = __ballot(kk[rr][s2] <= T[rr]);
        unsigned base = 0;
        #pragma unroll
        for (int s2 = 0; s2 < 8; ++s2) {
            if (kk[rr][s2] <= T[rr]) {
                unsigned pos = base + mbcnt_(bal[s2]);
                if (pos < 64u) scr[rr*64 + pos] = kk[rr][s2];
            }
            base += (unsigned)__popcll(bal[s2]);
        }
        cnt[rr] = base;
    }
    // same-wave LDS RAW ordered by lgkmcnt; no barrier needed

    // ---- Phase C: kill self, DPP max-removal of (actives-16) largest ----
    #pragma unroll
    for (int rr = 0; rr < 2; ++rr) {
        const unsigned cc_ = umin_(cnt[rr], 64u);
        const int ri = wid*2 + rr;
        const unsigned rowglob = (unsigned)(rowbase + ri);
        bool act = lane < (int)cc_;
        unsigned mv = act ? scr[rr*64 + lane] : 0u;   // 0 = inactive sentinel
        if (act && (mv & 511u) == rowglob) { act = false; mv = 0u; }  // self
        int e = __popcll(__ballot(act)) - 16;
        while (e > 0) {                               // wave-uniform, exp ~2
            unsigned mx = wmax64_(mv);                // VALU-pipe reduce
            if (mv == mx) { act = false; mv = 0u; }   // keys unique -> one lane
            --e;
        }
        int* outp = idxout + ((size_t)b*N_ + rowglob)*K_;
        unsigned long long bal = __ballot(act);       // exactly 16 lanes
        unsigned rank = mbcnt_(bal);
        if (act) outp[rank] = (int)(mv & 511u);
    }

    // ---- fused P/Q projection AFTER selection (hides in wave overlap) ----
    {
        const int t = wid & 3;
        f32x4 acc = (wid < 4) ? splat4(be[t*16+m]) : splat4(0.f);
        #pragma unroll
        for (int cc = 0; cc < 2; ++cc) {
            const f16x8 afc = cc ? af1 : af0;
            f16x8 bb;
            if (wid < 4) {
                #pragma unroll
                for (int jj = 0; jj < 8; ++jj) {
                    float wa = We[(q*8+jj+32*cc)*64 + t*16+m];
                    float wb = We[(q*8+jj+32*cc+64)*64 + t*16+m];
                    bb[jj] = (f16)(wa - wb);
                }
            } else {
                #pragma unroll
                for (int jj = 0; jj < 8; ++jj)
                    bb[jj] = (f16)We[(q*8+jj+32*cc+64)*64 + t*16+m];
            }
            acc = mfma16(afc, bb, acc);
        }
        f16* outp = (wid < 4) ? Pout : Qout;
        #pragma unroll
        for (int r = 0; r < 4; ++r)
            outp[((size_t)b*N_ + rowbase + q*4 + r)*64 + t*16 + m] = (f16)acc[r];
    }
}

// ---------------------------------------------------------------------------
// EdgeConv layer2 + sum aggregation + fused sq-norm. 2-node interleave: the
// pair's 8 fragment loads issue before either node's compute, so each node's
// gather latency hides under the sibling's MFMA+epilogue. DPP reductions.
// grid 2048 x block 256.
// ---------------------------------------------------------------------------
__device__ __forceinline__ void edge_node_(size_t r0, f16x8 pa, f16x8 pb,
        f16x8 qa, f16x8 qb, const f16x8 (&bf)[2][4], const float (&bcol)[4],
        f16* __restrict__ out, float* __restrict__ sqout, int lane)
{
    f16x8 af0 = elu8h_(pa + qa);
    f16x8 af1 = elu8h_(pb + qb);
    f32x4 acc[4];
    #pragma unroll
    for (int t = 0; t < 4; ++t) acc[t] = splat4(bcol[t]);
    #pragma unroll
    for (int t = 0; t < 4; ++t) acc[t] = mfma16(af0, bf[0][t], acc[t]);
    #pragma unroll
    for (int t = 0; t < 4; ++t) acc[t] = mfma16(af1, bf[1][t], acc[t]);
    float ssum = 0.f;
    #pragma unroll
    for (int t = 0; t < 4; ++t) {
        float s = elu_(acc[t][0]) + elu_(acc[t][1]) + elu_(acc[t][2]) + elu_(acc[t][3]);
        s += __shfl_xor(s, 16);
        s += __shfl_xor(s, 32);
        if (lane < 16) out[r0*64 + t*16 + lane] = (f16)s;
        ssum += s*s;
    }
    ssum = rsum16lo_(ssum);
    if (lane == 0) sqout[r0] = ssum;
}

__global__ __launch_bounds__(256, 5) void edge_kernel(const f16* __restrict__ P,
        const f16* __restrict__ Q, const int* __restrict__ idx,
        const float* __restrict__ W1, const float* __restrict__ b1,
        f16* __restrict__ out, float* __restrict__ sqout)
{
    const int lane = threadIdx.x & 63;
    const int wid  = threadIdx.x >> 6;
    const int m = lane & 15, q = lane >> 4;

    f16x8 bf[2][4];
    #pragma unroll
    for (int cc = 0; cc < 2; ++cc)
        #pragma unroll
        for (int t = 0; t < 4; ++t)
            #pragma unroll
            for (int jj = 0; jj < 8; ++jj)
                bf[cc][t][jj] = (f16)W1[(q*8 + jj + 32*cc)*64 + t*16 + m];
    float bcol[4];
    #pragma unroll
    for (int t = 0; t < 4; ++t) bcol[t] = b1[t*16 + m];

    const int node0 = blockIdx.x*32 + wid*8;
    const int gbase = node0 & ~(N_-1);
    const int c0a = q*8, c0b = q*8 + 32;
    int jv[8];
    #pragma unroll
    for (int i = 0; i < 8; ++i) jv[i] = idx[(size_t)(node0 + i)*K_ + m];

    #pragma unroll
    for (int ip = 0; ip < 4; ++ip) {
        const size_t r0 = (size_t)(node0 + 2*ip);
        const size_t r1 = r0 + 1;
        const size_t g0 = (size_t)(gbase + jv[2*ip]);
        const size_t g1 = (size_t)(gbase + jv[2*ip+1]);
        f16x8 p0a = *(const f16x8*)(P + r0*64 + c0a);
        f16x8 p0b = *(const f16x8*)(P + r0*64 + c0b);
        f16x8 q0a = *(const f16x8*)(Q + g0*64 + c0a);
        f16x8 q0b = *(const f16x8*)(Q + g0*64 + c0b);
        f16x8 p1a = *(const f16x8*)(P + r1*64 + c0a);
        f16x8 p1b = *(const f16x8*)(P + r1*64 + c0b);
        f16x8 q1a = *(const f16x8*)(Q + g1*64 + c0a);
        f16x8 q1b = *(const f16x8*)(Q + g1*64 + c0b);
        edge_node_(r0, p0a, p0b, q0a, q0b, bf, bcol, out, sqout, lane);
        edge_node_(r1, p1a, p1b, q1a, q1b, bf, bcol, out, sqout, lane);
    }
}

// ---------------------------------------------------------------------------
// Global max-pool (vectorized f16x8 loads + LDS tree) + 3-layer output MLP
// (4-way split dots) + log_softmax. grid 128 x block 256.
// ---------------------------------------------------------------------------
__global__ __launch_bounds__(256) void final_kernel(const f16* __restrict__ hin,
        const float* __restrict__ Wo0, const float* __restrict__ bo0,
        const float* __restrict__ Wo1, const float* __restrict__ bo1,
        const float* __restrict__ Wo2, const float* __restrict__ bo2,
        float* __restrict__ out)
{
    __shared__ float smax[32][64];
    __shared__ float g0[64], g1[64], g2[64], part[4][64], lg[10];
    const int t = threadIdx.x;
    const int b = blockIdx.x;
    const int cg = t & 7, rg = t >> 3;

    float mx[8];
    #pragma unroll
    for (int e = 0; e < 8; ++e) mx[e] = -3.0e38f;
    #pragma unroll
    for (int i = 0; i < 16; ++i) {
        const int row = rg + i*32;
        f16x8 vv = *(const f16x8*)(hin + ((size_t)b*N_ + row)*64 + cg*8);
        #pragma unroll
        for (int e = 0; e < 8; ++e) mx[e] = fmaxf(mx[e], (float)vv[e]);
    }
    #pragma unroll
    for (int e = 0; e < 8; ++e) smax[rg][cg*8 + e] = mx[e];
    __syncthreads();
    for (int s = 16; s >= 1; s >>= 1) {
        if (rg < s) {
            #pragma unroll
            for (int e = 0; e < 8; ++e)
                smax[rg][cg*8+e] = fmaxf(smax[rg][cg*8+e], smax[rg+s][cg*8+e]);
        }
        __syncthreads();
    }
    if (t < 64) g0[t] = smax[0][t];
    __syncthreads();

    const int j = t & 63, p = t >> 6;
    {
        float a = 0.f;
        #pragma unroll
        for (int c = 0; c < 16; ++c) a += g0[p*16 + c]*Wo0[(p*16 + c)*64 + j];
        part[p][j] = a;
    }
    __syncthreads();
    if (t < 64) g1[t] = elu_(part[0][t] + part[1][t] + part[2][t] + part[3][t] + bo0[t]);
    __syncthreads();
    {
        float a = 0.f;
        #pragma unroll
        for (int c = 0; c < 16; ++c) a += g1[p*16 + c]*Wo1[(p*16 + c)*64 + j];
        part[p][j] = a;
    }
    __syncthreads();
    if (t < 64) g2[t] = elu_(part[0][t] + part[1][t] + part[2][t] + part[3][t] + bo1[t]);
    __syncthreads();
    if (t < 10) { float a = bo2[t]; for (int c = 0; c < 64; ++c) a += g2[c]*Wo2[c*10 + t]; lg[t] = a; }
    __syncthreads();
    if (t == 0) {
        float mxl = lg[0];
        for (int i = 1; i < 10; ++i) mxl = fmaxf(mxl, lg[i]);
        float s = 0.f;
        for (int i = 0; i < 10; ++i) s += expf(lg[i] - mxl);
        const float lse = mxl + logf(s);
        for (int i = 0; i < 10; ++i) out[b*10 + i] = lg[i] - lse;
    }
}

extern "C" void kernel_launch(void* const* d_in, const int* in_sizes, int n_in,
                              void* d_out, int out_size, void* d_ws, size_t ws_size,
                              hipStream_t stream) {
    const float* x     = (const float*)d_in[0];
    const float* W_in0 = (const float*)d_in[1];
    const float* b_in0 = (const float*)d_in[2];
    const float* W_in1 = (const float*)d_in[3];
    const float* b_in1 = (const float*)d_in[4];
    const float* W_in2 = (const float*)d_in[5];
    const float* b_in2 = (const float*)d_in[6];
    const float* W_e0  = (const float*)d_in[7];   // [2,128,64]
    const float* b_e0  = (const float*)d_in[8];   // [2,64]
    const float* W_e1  = (const float*)d_in[9];   // [2,64,64]
    const float* b_e1  = (const float*)d_in[10];  // [2,64]
    const float* Wo0   = (const float*)d_in[11];
    const float* bo0   = (const float*)d_in[12];
    const float* Wo1   = (const float*)d_in[13];
    const float* bo1   = (const float*)d_in[14];
    const float* Wo2   = (const float*)d_in[15];
    const float* bo2   = (const float*)d_in[16];

    char* ws = (char*)d_ws;
    f16*   hA   = (f16*)(ws);                       // 8 MB
    f16*   hB   = (f16*)(ws + 8388608);             // 8 MB
    f16*   Pb   = (f16*)(ws + 16777216);            // 8 MB
    f16*   Qb   = (f16*)(ws + 25165824);            // 8 MB
    int*   idxb = (int*)(ws + 33554432);            // 4 MB
    float* sqb  = (float*)(ws + 37748736);          // 256 KB

    // fused input MLP + sq  (P0/Q0 now produced inside knn)
    mlp_kernel<<<1024, 256, 0, stream>>>(x, W_in0, b_in0, W_in1, b_in1, W_in2, b_in2,
                                         hA, sqb);
    // block 0 (knn fuses P0/Q0)
    knn_kernel<<<4096, 512, 0, stream>>>(hA, sqb, idxb, W_e0, b_e0, Pb, Qb);
    edge_kernel<<<2048, 256, 0, stream>>>(Pb, Qb, idxb, W_e1, b_e1, hB, sqb);
    // block 1 (knn fuses P1/Q1)
    knn_kernel<<<4096, 512, 0, stream>>>(hB, sqb, idxb, W_e0 + 8192, b_e0 + 64, Pb, Qb);
    edge_kernel<<<2048, 256, 0, stream>>>(Pb, Qb, idxb, W_e1 + 4096, b_e1 + 64, hA, sqb);

    final_kernel<<<128, 256, 0, stream>>>(hA, Wo0, bo0, Wo1, bo1, Wo2, bo2, (float*)d_out);
}